// Round 1
// baseline (297.054 us; speedup 1.0000x reference)
//
#include <hip/hip_runtime.h>

// B=4, C=512, L=2048, H=8, D=64. f32 inputs, f32 output.
// transpA: one launch: x->xT[b][l][c], w_qkv->wT[f][c], w_out->woT[f][c] (bf16)
// qkvgemm: bf16 MFMA direct-global frags -> QT[l][d]*0.125*log2e, KT[l][d], V[d][l]
// attn: transposed dataflow S^T=K.Q^T, O^T=V.P^T; 32 i-rows/wave; v_exp_f32;
//       register-prefetch pipeline (hides L2 latency) AND *** LDS-free P:
//       K rows are loaded with permutation perm(jt,m)=(jt&1)*32+(m>>2)*8+(jt>>1)*4+(m&3)
//       so the S^T output lands with lane (i,q) holding exactly the PV B-fragment
//       j-slots {kj*32+q*8..+7}. j is a contraction index in both softmax-sum and PV,
//       so any j-permutation shared by K and V is exact. Deletes 8 ds_write_b64 +
//       4 ds_read_b128 + lgkmcnt wait + 3.1M bank-conflict cycles per dispatch. ***
// outgemm: bf16 MFMA direct-global frags, bias, f32 store

#define LDIM 2048
#define CDIM 512
#define BATCH 4

typedef __attribute__((ext_vector_type(8))) short s16x8;
typedef __attribute__((ext_vector_type(4))) float f32x4;
typedef __attribute__((ext_vector_type(4))) unsigned short u16x4;
typedef unsigned int u32;
typedef unsigned short u16;

__device__ __forceinline__ u16 f2b(float f) {
    unsigned u = __float_as_uint(f);
    u += 0x7fffu + ((u >> 16) & 1u);   // RNE
    return (u16)(u >> 16);
}
// pack two floats -> two bf16 (round-half-up) in one u32 (b in high half)
__device__ __forceinline__ u32 pk2(float a, float b) {
    u32 ua = __float_as_uint(a) + 0x8000u;
    u32 ub = __float_as_uint(b) + 0x8000u;
    return __builtin_amdgcn_perm(ub, ua, 0x07060302u);  // {ub.hi16, ua.hi16}
}

// ---------------- unified transpose + f32->bf16 convert ----------------
__global__ __launch_bounds__(256)
void transpA_k(const float* __restrict__ x, const float* __restrict__ wq,
               const float* __restrict__ wo, u16* __restrict__ xT,
               u16* __restrict__ wT, u16* __restrict__ woT)
{
    const int r0 = blockIdx.x * 64;
    const int y  = blockIdx.y;
    const float* in; u16* out; int inLD, c0;
    if (y < 128) {
        const int b = y >> 5, ct = y & 31;
        in = x + (size_t)b * CDIM * LDIM; inLD = LDIM; c0 = ct * 64;
        out = xT + (size_t)b * LDIM * CDIM;
    } else if (y < 152) {
        in = wq; inLD = 1536; c0 = (y - 128) * 64; out = wT;
    } else {
        in = wo; inLD = 512;  c0 = (y - 152) * 64; out = woT;
    }

    __shared__ __align__(16) u16 t[64][80];
    const int tt = threadIdx.x;
    const int lr = tt >> 4, lc = (tt & 15) * 4;
    #pragma unroll
    for (int i = 0; i < 4; ++i) {
        f32x4 v = *(const f32x4*)(in + (size_t)(r0 + lr + i * 16) * inLD + c0 + lc);
        #pragma unroll
        for (int j = 0; j < 4; ++j) t[lc + j][lr + i * 16] = f2b(v[j]);
    }
    __syncthreads();
    const int orow = tt >> 2, ocg = (tt & 3) * 16;
    s16x8 v0 = *(const s16x8*)&t[orow][ocg];
    s16x8 v1 = *(const s16x8*)&t[orow][ocg + 8];
    u16* dst = out + (size_t)(c0 + orow) * CDIM + r0 + ocg;
    *(s16x8*)dst = v0;
    *(s16x8*)(dst + 8) = v1;
}

// ---------------- QKV GEMM (unchanged) ----------------
__global__ __launch_bounds__(256)
void qkvgemm_bf16(const u16* __restrict__ xT, const u16* __restrict__ wT,
                  u16* __restrict__ QT, u16* __restrict__ KT, u16* __restrict__ V)
{
    const int f0 = blockIdx.x * 64;
    const int l0 = blockIdx.y * 128;
    const int b  = blockIdx.z;
    const u16* xTb = xT + (size_t)b * LDIM * CDIM;
    const int t = threadIdx.x, w = t >> 6, lane = t & 63;
    const int mn = lane & 15, q = lane >> 4;
    const bool vpart = (f0 >= 1024);

    const u16 *Abase, *Bbase;
    int mbase, nbase;
    if (!vpart) {
        mbase = f0 + (w >> 1) * 32; nbase = l0 + (w & 1) * 64;
        Abase = wT + (size_t)mbase * CDIM; Bbase = xTb + (size_t)nbase * CDIM;
    } else {
        mbase = l0 + w * 32; nbase = f0;
        Abase = xTb + (size_t)mbase * CDIM; Bbase = wT + (size_t)nbase * CDIM;
    }

    f32x4 acc[2][4] = {};
    #pragma unroll 2
    for (int c0 = 0; c0 < CDIM; c0 += 32) {
        s16x8 a[2], bf[4];
        #pragma unroll
        for (int mi = 0; mi < 2; ++mi)
            a[mi] = *(const s16x8*)(Abase + (size_t)(mi * 16 + mn) * CDIM + c0 + q * 8);
        #pragma unroll
        for (int ni = 0; ni < 4; ++ni)
            bf[ni] = *(const s16x8*)(Bbase + (size_t)(ni * 16 + mn) * CDIM + c0 + q * 8);
        #pragma unroll
        for (int mi = 0; mi < 2; ++mi)
            #pragma unroll
            for (int ni = 0; ni < 4; ++ni)
                acc[mi][ni] = __builtin_amdgcn_mfma_f32_16x16x32_bf16(a[mi], bf[ni], acc[mi][ni], 0, 0, 0);
    }

    if (!vpart) {
        const int part = f0 >> 9;
        const float sc2 = (part == 0) ? 0.18033688f : 1.0f;  // 0.125*log2(e)
        u16* Tout = (part == 0) ? QT : KT;
        #pragma unroll
        for (int mi = 0; mi < 2; ++mi) {
            const int fg0 = mbase + mi * 16;
            const int h = (fg0 >> 6) & 7;
            const int d0 = (fg0 & 63) + q * 4;
            u16* T = Tout + (size_t)(b * 8 + h) * LDIM * 64;
            #pragma unroll
            for (int ni = 0; ni < 4; ++ni) {
                const int lg = nbase + ni * 16 + mn;
                u16x4 pk;
                #pragma unroll
                for (int r = 0; r < 4; ++r) pk[r] = f2b(acc[mi][ni][r] * sc2);
                *(u16x4*)(T + (size_t)lg * 64 + d0) = pk;
            }
        }
    } else {
        #pragma unroll
        for (int ni = 0; ni < 4; ++ni) {
            const int fg = nbase + ni * 16 + mn;
            const int h = (fg >> 6) & 7;
            const int d = fg & 63;
            u16* Vb = V + (size_t)((b * 8 + h) * 64 + d) * LDIM;
            #pragma unroll
            for (int mi = 0; mi < 2; ++mi) {
                const int lg0 = mbase + mi * 16 + q * 4;
                u16x4 pk;
                #pragma unroll
                for (int r = 0; r < 4; ++r) pk[r] = f2b(acc[mi][ni][r]);
                *(u16x4*)(Vb + lg0) = pk;
            }
        }
    }
}

// ---------------- Flash attention: LDS-free, prefetch-pipelined, 32 i-rows/wave --
// grid (x=bh 32, y=64), 64 threads (1 wave). block_id % 8 == h: XCD head pinning.
// K rows permuted so P stays lane-local (see header comment). V stays identity.
__global__ __launch_bounds__(64)
void attn_k(const u16* __restrict__ QT, const u16* __restrict__ KT,
            const u16* __restrict__ V, u16* __restrict__ aoT)
{
    const int bh = blockIdx.x;
    const int b = bh >> 3, h = bh & 7;
    const u16* Qh = QT + (size_t)bh * LDIM * 64;
    const u16* Kh = KT + (size_t)bh * LDIM * 64;
    const u16* Vh = V  + (size_t)bh * 64 * LDIM;

    const int lane = threadIdx.x;
    const int mn = lane & 15, q = lane >> 4;
    const int iw = blockIdx.y * 32;

    // perm(jt, mn): K-row permutation within the 64-j tile (shared by S and PV
    // via identity-ordered V contraction; exact since j is a reduction index).
    int kperm[4];
    {
        const int base = (mn >> 2) * 8 + (mn & 3);
        #pragma unroll
        for (int jt = 0; jt < 4; ++jt)
            kperm[jt] = (jt & 1) * 32 + ((jt >> 1) << 2) + base;
    }

    s16x8 aq[2][2];
    #pragma unroll
    for (int ibt = 0; ibt < 2; ++ibt)
        #pragma unroll
        for (int kd = 0; kd < 2; ++kd)
            aq[ibt][kd] = *(const s16x8*)(Qh + (size_t)(iw + ibt * 16 + mn) * 64 + kd * 32 + q * 8);

    f32x4 o_acc[2][4] = {};
    float lp[2] = {0.f, 0.f};

    // preload iteration-0 K/V fragments (K rows permuted)
    s16x8 kc[2][4], vc[2][4];
    #pragma unroll
    for (int kd = 0; kd < 2; ++kd)
        #pragma unroll
        for (int jt = 0; jt < 4; ++jt)
            kc[kd][jt] = *(const s16x8*)(Kh + (size_t)kperm[jt] * 64 + kd * 32 + q * 8);
    #pragma unroll
    for (int kj = 0; kj < 2; ++kj)
        #pragma unroll
        for (int dt = 0; dt < 4; ++dt)
            vc[kj][dt] = *(const s16x8*)(Vh + (size_t)(dt * 16 + mn) * LDIM + kj * 32 + q * 8);

    #pragma unroll 2
    for (int j0 = 0; j0 < LDIM; j0 += 64) {
        const int jn = (j0 + 64) & (LDIM - 1);   // last iter wraps to 0 (harmless, L2-hot)

        // issue next tile's loads FIRST (one full iteration of latency hiding)
        s16x8 kn[2][4], vn[2][4];
        #pragma unroll
        for (int kd = 0; kd < 2; ++kd)
            #pragma unroll
            for (int jt = 0; jt < 4; ++jt)
                kn[kd][jt] = *(const s16x8*)(Kh + (size_t)(jn + kperm[jt]) * 64 + kd * 32 + q * 8);
        #pragma unroll
        for (int kj = 0; kj < 2; ++kj)
            #pragma unroll
            for (int dt = 0; dt < 4; ++dt)
                vn[kj][dt] = *(const s16x8*)(Vh + (size_t)(dt * 16 + mn) * LDIM + jn + kj * 32 + q * 8);

        // S^T = K.Q^T on current K (jt MFMA covers permuted j-rows)
        f32x4 s[2][4] = {};
        #pragma unroll
        for (int kd = 0; kd < 2; ++kd)
            #pragma unroll
            for (int jt = 0; jt < 4; ++jt) {
                s[0][jt] = __builtin_amdgcn_mfma_f32_16x16x32_bf16(kc[kd][jt], aq[0][kd], s[0][jt], 0, 0, 0);
                s[1][jt] = __builtin_amdgcn_mfma_f32_16x16x32_bf16(kc[kd][jt], aq[1][kd], s[1][jt], 0, 0, 0);
            }

        // p = 2^s; build PV B-fragments fully in-register.
        // Lane (mn,q) holds s[ibt][jt][r] = S^T at j = j0 + (jt&1)*32 + q*8 + (jt>>1)*4 + r,
        // exactly the B-frag slot (kj=jt&1, idx=(jt>>1)*4+r). No LDS round-trip.
        #pragma unroll
        for (int kj = 0; kj < 2; ++kj) {
            s16x8 ap[2];
            #pragma unroll
            for (int ibt = 0; ibt < 2; ++ibt) {
                float pa0 = __builtin_amdgcn_exp2f(s[ibt][kj][0]);
                float pa1 = __builtin_amdgcn_exp2f(s[ibt][kj][1]);
                float pa2 = __builtin_amdgcn_exp2f(s[ibt][kj][2]);
                float pa3 = __builtin_amdgcn_exp2f(s[ibt][kj][3]);
                float pb0 = __builtin_amdgcn_exp2f(s[ibt][kj + 2][0]);
                float pb1 = __builtin_amdgcn_exp2f(s[ibt][kj + 2][1]);
                float pb2 = __builtin_amdgcn_exp2f(s[ibt][kj + 2][2]);
                float pb3 = __builtin_amdgcn_exp2f(s[ibt][kj + 2][3]);
                lp[ibt] += ((pa0 + pa1) + (pa2 + pa3)) + ((pb0 + pb1) + (pb2 + pb3));
                union { s16x8 v; u32 w[4]; } u;
                u.w[0] = pk2(pa0, pa1);
                u.w[1] = pk2(pa2, pa3);
                u.w[2] = pk2(pb0, pb1);
                u.w[3] = pk2(pb2, pb3);
                ap[ibt] = u.v;
            }
            #pragma unroll
            for (int dt = 0; dt < 4; ++dt) {
                o_acc[0][dt] = __builtin_amdgcn_mfma_f32_16x16x32_bf16(vc[kj][dt], ap[0], o_acc[0][dt], 0, 0, 0);
                o_acc[1][dt] = __builtin_amdgcn_mfma_f32_16x16x32_bf16(vc[kj][dt], ap[1], o_acc[1][dt], 0, 0, 0);
            }
        }

        // rotate prefetched registers
        #pragma unroll
        for (int kd = 0; kd < 2; ++kd)
            #pragma unroll
            for (int jt = 0; jt < 4; ++jt)
                kc[kd][jt] = kn[kd][jt];
        #pragma unroll
        for (int kj = 0; kj < 2; ++kj)
            #pragma unroll
            for (int dt = 0; dt < 4; ++dt)
                vc[kj][dt] = vn[kj][dt];
    }

    #pragma unroll
    for (int ibt = 0; ibt < 2; ++ibt) {
        lp[ibt] += __shfl_xor(lp[ibt], 16);
        lp[ibt] += __shfl_xor(lp[ibt], 32);
    }

    #pragma unroll
    for (int ibt = 0; ibt < 2; ++ibt) {
        const float rinv = 1.0f / lp[ibt];
        u16* dst = aoT + ((size_t)b * LDIM + iw + ibt * 16 + mn) * 512 + h * 64 + q * 4;
        #pragma unroll
        for (int dt = 0; dt < 4; ++dt) {
            u16x4 pk;
            #pragma unroll
            for (int r = 0; r < 4; ++r)
                pk[r] = f2b(o_acc[ibt][dt][r] * rinv);
            *(u16x4*)(dst + dt * 16) = pk;
        }
    }
}

// ---------------- Output GEMM (unchanged) ----------------
__global__ __launch_bounds__(256)
void outgemm_d(const u16* __restrict__ aoT, const u16* __restrict__ woT,
               const float* __restrict__ bias, float* __restrict__ Y)
{
    const int f0 = blockIdx.x * 64;
    const int l0 = blockIdx.y * 128;
    const int b  = blockIdx.z;
    const int t = threadIdx.x, w = t >> 6, lane = t & 63;
    const int mn = lane & 15, q = lane >> 4;
    const int mbase = f0 + (w >> 1) * 32;
    const int nbase = l0 + (w & 1) * 64;
    const u16* Abase = woT + (size_t)mbase * CDIM;
    const u16* Bbase = aoT + ((size_t)b * LDIM + nbase) * CDIM;
    float* Yb = Y + (size_t)b * CDIM * LDIM;

    f32x4 acc[2][4] = {};
    #pragma unroll 2
    for (int c0 = 0; c0 < CDIM; c0 += 32) {
        s16x8 a[2], bf[4];
        #pragma unroll
        for (int mi = 0; mi < 2; ++mi)
            a[mi] = *(const s16x8*)(Abase + (size_t)(mi * 16 + mn) * CDIM + c0 + q * 8);
        #pragma unroll
        for (int ni = 0; ni < 4; ++ni)
            bf[ni] = *(const s16x8*)(Bbase + (size_t)(ni * 16 + mn) * CDIM + c0 + q * 8);
        #pragma unroll
        for (int mi = 0; mi < 2; ++mi)
            #pragma unroll
            for (int ni = 0; ni < 4; ++ni)
                acc[mi][ni] = __builtin_amdgcn_mfma_f32_16x16x32_bf16(a[mi], bf[ni], acc[mi][ni], 0, 0, 0);
    }
    #pragma unroll
    for (int mi = 0; mi < 2; ++mi)
        #pragma unroll
        for (int r = 0; r < 4; ++r) {
            const int f = mbase + mi * 16 + q * 4 + r;
            const float bs = bias[f];
            #pragma unroll
            for (int ni = 0; ni < 4; ++ni)
                Yb[(size_t)f * LDIM + nbase + ni * 16 + mn] = acc[mi][ni][r] + bs;
        }
}

extern "C" void kernel_launch(void* const* d_in, const int* in_sizes, int n_in,
                              void* d_out, int out_size, void* d_ws, size_t ws_size,
                              hipStream_t stream) {
    const float *x = nullptr, *w_qkv = nullptr, *w_out = nullptr, *b_out = nullptr;
    for (int i = 0; i < n_in; ++i) {
        switch (in_sizes[i]) {
            case 4 * 512 * 2048: x     = (const float*)d_in[i]; break;
            case 512 * 1536:     w_qkv = (const float*)d_in[i]; break;
            case 512 * 512:      w_out = (const float*)d_in[i]; break;
            case 512:            b_out = (const float*)d_in[i]; break;
        }
    }
    float* out = (float*)d_out;                 // [4][512][2048] f32

    const size_t SLAB = (size_t)BATCH * LDIM * 512;      // 4194304 elems
    u16* woT = (u16*)d_ws;                               // [512][512]
    u16* xT  = woT + (size_t)512 * 512;                  // [4][2048][512]
    u16* wT  = xT + SLAB;                                // [1536][512]
    u16* QT  = wT + (size_t)1536 * 512;                  // [32][2048][64]
    u16* KT  = QT + SLAB;                                // [32][2048][64]
    u16* V   = KT + SLAB;                                // [32][64][2048]
    u16* aoT = V + SLAB;                                 // [4][2048][512]

    transpA_k<<<dim3(8, 160), 256, 0, stream>>>(x, w_qkv, w_out, xT, wT, woT);
    qkvgemm_bf16<<<dim3(24, 16, BATCH), 256, 0, stream>>>(xT, wT, QT, KT, V);
    attn_k<<<dim3(BATCH * 8, LDIM / 32), 64, 0, stream>>>(QT, KT, V, aoT);
    outgemm_d<<<dim3(8, 16, BATCH), 256, 0, stream>>>(aoT, woT, b_out, out);
}

// Round 2
// 292.764 us; speedup vs baseline: 1.0147x; 1.0147x over previous
//
#include <hip/hip_runtime.h>

// B=4, C=512, L=2048, H=8, D=64. f32 inputs, f32 output.
// transpA: one launch: x->xT[b][l][c], w_qkv->wT[f][c], w_out->woT[f][c] (bf16)
// qkvgemm: bf16 MFMA direct-global frags -> QT[l][d]*0.125*log2e, KT[l][d], V[d][l]
// attn: transposed dataflow S^T=K.Q^T, O^T=V.P^T; 32 i-rows/block; v_exp_f32;
//       LDS-free P via K-row permutation (see r0); register-prefetch pipeline;
//       *** j-SPLIT ACROSS 2 WAVES: occupancy was the r1 bottleneck (2 waves/SIMD,
//       85% idle, 9.9k cyc/iter vs ~650 of work). Softmax here is sum-normalized
//       (no running max), so j-partials combine by plain addition: each wave does
//       half the j-range, partial (O,lp) merged through padded LDS at the end.
//       4096 waves = 16/CU = the VGPR<=128 occupancy cap. ***
// outgemm: bf16 MFMA direct-global frags, bias, f32 store

#define LDIM 2048
#define CDIM 512
#define BATCH 4

typedef __attribute__((ext_vector_type(8))) short s16x8;
typedef __attribute__((ext_vector_type(4))) float f32x4;
typedef __attribute__((ext_vector_type(4))) unsigned short u16x4;
typedef unsigned int u32;
typedef unsigned short u16;

__device__ __forceinline__ u16 f2b(float f) {
    unsigned u = __float_as_uint(f);
    u += 0x7fffu + ((u >> 16) & 1u);   // RNE
    return (u16)(u >> 16);
}
// pack two floats -> two bf16 (round-half-up) in one u32 (b in high half)
__device__ __forceinline__ u32 pk2(float a, float b) {
    u32 ua = __float_as_uint(a) + 0x8000u;
    u32 ub = __float_as_uint(b) + 0x8000u;
    return __builtin_amdgcn_perm(ub, ua, 0x07060302u);  // {ub.hi16, ua.hi16}
}

// ---------------- unified transpose + f32->bf16 convert ----------------
__global__ __launch_bounds__(256)
void transpA_k(const float* __restrict__ x, const float* __restrict__ wq,
               const float* __restrict__ wo, u16* __restrict__ xT,
               u16* __restrict__ wT, u16* __restrict__ woT)
{
    const int r0 = blockIdx.x * 64;
    const int y  = blockIdx.y;
    const float* in; u16* out; int inLD, c0;
    if (y < 128) {
        const int b = y >> 5, ct = y & 31;
        in = x + (size_t)b * CDIM * LDIM; inLD = LDIM; c0 = ct * 64;
        out = xT + (size_t)b * LDIM * CDIM;
    } else if (y < 152) {
        in = wq; inLD = 1536; c0 = (y - 128) * 64; out = wT;
    } else {
        in = wo; inLD = 512;  c0 = (y - 152) * 64; out = woT;
    }

    __shared__ __align__(16) u16 t[64][80];
    const int tt = threadIdx.x;
    const int lr = tt >> 4, lc = (tt & 15) * 4;
    #pragma unroll
    for (int i = 0; i < 4; ++i) {
        f32x4 v = *(const f32x4*)(in + (size_t)(r0 + lr + i * 16) * inLD + c0 + lc);
        #pragma unroll
        for (int j = 0; j < 4; ++j) t[lc + j][lr + i * 16] = f2b(v[j]);
    }
    __syncthreads();
    const int orow = tt >> 2, ocg = (tt & 3) * 16;
    s16x8 v0 = *(const s16x8*)&t[orow][ocg];
    s16x8 v1 = *(const s16x8*)&t[orow][ocg + 8];
    u16* dst = out + (size_t)(c0 + orow) * CDIM + r0 + ocg;
    *(s16x8*)dst = v0;
    *(s16x8*)(dst + 8) = v1;
}

// ---------------- QKV GEMM (unchanged) ----------------
__global__ __launch_bounds__(256)
void qkvgemm_bf16(const u16* __restrict__ xT, const u16* __restrict__ wT,
                  u16* __restrict__ QT, u16* __restrict__ KT, u16* __restrict__ V)
{
    const int f0 = blockIdx.x * 64;
    const int l0 = blockIdx.y * 128;
    const int b  = blockIdx.z;
    const u16* xTb = xT + (size_t)b * LDIM * CDIM;
    const int t = threadIdx.x, w = t >> 6, lane = t & 63;
    const int mn = lane & 15, q = lane >> 4;
    const bool vpart = (f0 >= 1024);

    const u16 *Abase, *Bbase;
    int mbase, nbase;
    if (!vpart) {
        mbase = f0 + (w >> 1) * 32; nbase = l0 + (w & 1) * 64;
        Abase = wT + (size_t)mbase * CDIM; Bbase = xTb + (size_t)nbase * CDIM;
    } else {
        mbase = l0 + w * 32; nbase = f0;
        Abase = xTb + (size_t)mbase * CDIM; Bbase = wT + (size_t)nbase * CDIM;
    }

    f32x4 acc[2][4] = {};
    #pragma unroll 2
    for (int c0 = 0; c0 < CDIM; c0 += 32) {
        s16x8 a[2], bf[4];
        #pragma unroll
        for (int mi = 0; mi < 2; ++mi)
            a[mi] = *(const s16x8*)(Abase + (size_t)(mi * 16 + mn) * CDIM + c0 + q * 8);
        #pragma unroll
        for (int ni = 0; ni < 4; ++ni)
            bf[ni] = *(const s16x8*)(Bbase + (size_t)(ni * 16 + mn) * CDIM + c0 + q * 8);
        #pragma unroll
        for (int mi = 0; mi < 2; ++mi)
            #pragma unroll
            for (int ni = 0; ni < 4; ++ni)
                acc[mi][ni] = __builtin_amdgcn_mfma_f32_16x16x32_bf16(a[mi], bf[ni], acc[mi][ni], 0, 0, 0);
    }

    if (!vpart) {
        const int part = f0 >> 9;
        const float sc2 = (part == 0) ? 0.18033688f : 1.0f;  // 0.125*log2(e)
        u16* Tout = (part == 0) ? QT : KT;
        #pragma unroll
        for (int mi = 0; mi < 2; ++mi) {
            const int fg0 = mbase + mi * 16;
            const int h = (fg0 >> 6) & 7;
            const int d0 = (fg0 & 63) + q * 4;
            u16* T = Tout + (size_t)(b * 8 + h) * LDIM * 64;
            #pragma unroll
            for (int ni = 0; ni < 4; ++ni) {
                const int lg = nbase + ni * 16 + mn;
                u16x4 pk;
                #pragma unroll
                for (int r = 0; r < 4; ++r) pk[r] = f2b(acc[mi][ni][r] * sc2);
                *(u16x4*)(T + (size_t)lg * 64 + d0) = pk;
            }
        }
    } else {
        #pragma unroll
        for (int ni = 0; ni < 4; ++ni) {
            const int fg = nbase + ni * 16 + mn;
            const int h = (fg >> 6) & 7;
            const int d = fg & 63;
            u16* Vb = V + (size_t)((b * 8 + h) * 64 + d) * LDIM;
            #pragma unroll
            for (int mi = 0; mi < 2; ++mi) {
                const int lg0 = mbase + mi * 16 + q * 4;
                u16x4 pk;
                #pragma unroll
                for (int r = 0; r < 4; ++r) pk[r] = f2b(acc[mi][ni][r]);
                *(u16x4*)(Vb + lg0) = pk;
            }
        }
    }
}

// ---------------- Flash attention: LDS-free P, 2-wave j-split, 32 i-rows/block --
// grid (x=bh 32, y=64), 128 threads (2 waves). block_id % 8 == h: XCD head pinning.
// Wave w handles j in [w*1024, (w+1)*1024); partials combine by addition via LDS.
__global__ __launch_bounds__(128)
void attn_k(const u16* __restrict__ QT, const u16* __restrict__ KT,
            const u16* __restrict__ V, u16* __restrict__ aoT)
{
    const int bh = blockIdx.x;
    const int b = bh >> 3, h = bh & 7;
    const u16* Qh = QT + (size_t)bh * LDIM * 64;
    const u16* Kh = KT + (size_t)bh * LDIM * 64;
    const u16* Vh = V  + (size_t)bh * 64 * LDIM;

    __shared__ __align__(16) float o_sh[32][68];   // +4 pad: 16-way -> 2-way (free)
    __shared__ float lp_sh[32];

    const int tid = threadIdx.x;
    const int wv = tid >> 6;
    const int lane = tid & 63;
    const int mn = lane & 15, q = lane >> 4;
    const int iw = blockIdx.y * 32;
    const int JH = LDIM / 2;             // per-wave j-range
    const int jbase = wv * JH;

    // perm(jt, mn): K-row permutation within the 64-j tile (shared by S and PV
    // via identity-ordered V contraction; exact since j is a reduction index).
    int kperm[4];
    {
        const int base = (mn >> 2) * 8 + (mn & 3);
        #pragma unroll
        for (int jt = 0; jt < 4; ++jt)
            kperm[jt] = (jt & 1) * 32 + ((jt >> 1) << 2) + base;
    }

    s16x8 aq[2][2];
    #pragma unroll
    for (int ibt = 0; ibt < 2; ++ibt)
        #pragma unroll
        for (int kd = 0; kd < 2; ++kd)
            aq[ibt][kd] = *(const s16x8*)(Qh + (size_t)(iw + ibt * 16 + mn) * 64 + kd * 32 + q * 8);

    f32x4 o_acc[2][4] = {};
    float lp[2] = {0.f, 0.f};

    // preload this wave's iteration-0 K/V fragments (K rows permuted)
    s16x8 kc[2][4], vc[2][4];
    #pragma unroll
    for (int kd = 0; kd < 2; ++kd)
        #pragma unroll
        for (int jt = 0; jt < 4; ++jt)
            kc[kd][jt] = *(const s16x8*)(Kh + (size_t)(jbase + kperm[jt]) * 64 + kd * 32 + q * 8);
    #pragma unroll
    for (int kj = 0; kj < 2; ++kj)
        #pragma unroll
        for (int dt = 0; dt < 4; ++dt)
            vc[kj][dt] = *(const s16x8*)(Vh + (size_t)(dt * 16 + mn) * LDIM + jbase + kj * 32 + q * 8);

    #pragma unroll 2
    for (int jj = 0; jj < JH; jj += 64) {
        const int jn = jbase + ((jj + 64) & (JH - 1));   // last iter wraps (L2-hot, harmless)

        // issue next tile's loads FIRST (one full iteration of latency hiding)
        s16x8 kn[2][4], vn[2][4];
        #pragma unroll
        for (int kd = 0; kd < 2; ++kd)
            #pragma unroll
            for (int jt = 0; jt < 4; ++jt)
                kn[kd][jt] = *(const s16x8*)(Kh + (size_t)(jn + kperm[jt]) * 64 + kd * 32 + q * 8);
        #pragma unroll
        for (int kj = 0; kj < 2; ++kj)
            #pragma unroll
            for (int dt = 0; dt < 4; ++dt)
                vn[kj][dt] = *(const s16x8*)(Vh + (size_t)(dt * 16 + mn) * LDIM + jn + kj * 32 + q * 8);

        // S^T = K.Q^T on current K (jt MFMA covers permuted j-rows)
        f32x4 s[2][4] = {};
        #pragma unroll
        for (int kd = 0; kd < 2; ++kd)
            #pragma unroll
            for (int jt = 0; jt < 4; ++jt) {
                s[0][jt] = __builtin_amdgcn_mfma_f32_16x16x32_bf16(kc[kd][jt], aq[0][kd], s[0][jt], 0, 0, 0);
                s[1][jt] = __builtin_amdgcn_mfma_f32_16x16x32_bf16(kc[kd][jt], aq[1][kd], s[1][jt], 0, 0, 0);
            }

        // p = 2^s; build PV B-fragments fully in-register (lane-local j-slots).
        #pragma unroll
        for (int kj = 0; kj < 2; ++kj) {
            s16x8 ap[2];
            #pragma unroll
            for (int ibt = 0; ibt < 2; ++ibt) {
                float pa0 = __builtin_amdgcn_exp2f(s[ibt][kj][0]);
                float pa1 = __builtin_amdgcn_exp2f(s[ibt][kj][1]);
                float pa2 = __builtin_amdgcn_exp2f(s[ibt][kj][2]);
                float pa3 = __builtin_amdgcn_exp2f(s[ibt][kj][3]);
                float pb0 = __builtin_amdgcn_exp2f(s[ibt][kj + 2][0]);
                float pb1 = __builtin_amdgcn_exp2f(s[ibt][kj + 2][1]);
                float pb2 = __builtin_amdgcn_exp2f(s[ibt][kj + 2][2]);
                float pb3 = __builtin_amdgcn_exp2f(s[ibt][kj + 2][3]);
                lp[ibt] += ((pa0 + pa1) + (pa2 + pa3)) + ((pb0 + pb1) + (pb2 + pb3));
                union { s16x8 v; u32 w[4]; } u;
                u.w[0] = pk2(pa0, pa1);
                u.w[1] = pk2(pa2, pa3);
                u.w[2] = pk2(pb0, pb1);
                u.w[3] = pk2(pb2, pb3);
                ap[ibt] = u.v;
            }
            #pragma unroll
            for (int dt = 0; dt < 4; ++dt) {
                o_acc[0][dt] = __builtin_amdgcn_mfma_f32_16x16x32_bf16(vc[kj][dt], ap[0], o_acc[0][dt], 0, 0, 0);
                o_acc[1][dt] = __builtin_amdgcn_mfma_f32_16x16x32_bf16(vc[kj][dt], ap[1], o_acc[1][dt], 0, 0, 0);
            }
        }

        // rotate prefetched registers
        #pragma unroll
        for (int kd = 0; kd < 2; ++kd)
            #pragma unroll
            for (int jt = 0; jt < 4; ++jt)
                kc[kd][jt] = kn[kd][jt];
        #pragma unroll
        for (int kj = 0; kj < 2; ++kj)
            #pragma unroll
            for (int dt = 0; dt < 4; ++dt)
                vc[kj][dt] = vn[kj][dt];
    }

    #pragma unroll
    for (int ibt = 0; ibt < 2; ++ibt) {
        lp[ibt] += __shfl_xor(lp[ibt], 16);
        lp[ibt] += __shfl_xor(lp[ibt], 32);
    }

    // combine the two waves' j-partials: plain addition (sum-normalized softmax)
    if (wv == 1) {
        #pragma unroll
        for (int ibt = 0; ibt < 2; ++ibt) {
            #pragma unroll
            for (int dt = 0; dt < 4; ++dt)
                *(f32x4*)&o_sh[ibt * 16 + mn][dt * 16 + q * 4] = o_acc[ibt][dt];
            if (q == 0) lp_sh[ibt * 16 + mn] = lp[ibt];
        }
    }
    __syncthreads();
    if (wv == 0) {
        #pragma unroll
        for (int ibt = 0; ibt < 2; ++ibt) {
            const float rinv = 1.0f / (lp[ibt] + lp_sh[ibt * 16 + mn]);
            u16* dst = aoT + ((size_t)b * LDIM + iw + ibt * 16 + mn) * 512 + h * 64 + q * 4;
            #pragma unroll
            for (int dt = 0; dt < 4; ++dt) {
                f32x4 os = *(const f32x4*)&o_sh[ibt * 16 + mn][dt * 16 + q * 4];
                u16x4 pk;
                #pragma unroll
                for (int r = 0; r < 4; ++r)
                    pk[r] = f2b((o_acc[ibt][dt][r] + os[r]) * rinv);
                *(u16x4*)(dst + dt * 16) = pk;
            }
        }
    }
}

// ---------------- Output GEMM (unchanged) ----------------
__global__ __launch_bounds__(256)
void outgemm_d(const u16* __restrict__ aoT, const u16* __restrict__ woT,
               const float* __restrict__ bias, float* __restrict__ Y)
{
    const int f0 = blockIdx.x * 64;
    const int l0 = blockIdx.y * 128;
    const int b  = blockIdx.z;
    const int t = threadIdx.x, w = t >> 6, lane = t & 63;
    const int mn = lane & 15, q = lane >> 4;
    const int mbase = f0 + (w >> 1) * 32;
    const int nbase = l0 + (w & 1) * 64;
    const u16* Abase = woT + (size_t)mbase * CDIM;
    const u16* Bbase = aoT + ((size_t)b * LDIM + nbase) * CDIM;
    float* Yb = Y + (size_t)b * CDIM * LDIM;

    f32x4 acc[2][4] = {};
    #pragma unroll 2
    for (int c0 = 0; c0 < CDIM; c0 += 32) {
        s16x8 a[2], bf[4];
        #pragma unroll
        for (int mi = 0; mi < 2; ++mi)
            a[mi] = *(const s16x8*)(Abase + (size_t)(mi * 16 + mn) * CDIM + c0 + q * 8);
        #pragma unroll
        for (int ni = 0; ni < 4; ++ni)
            bf[ni] = *(const s16x8*)(Bbase + (size_t)(ni * 16 + mn) * CDIM + c0 + q * 8);
        #pragma unroll
        for (int mi = 0; mi < 2; ++mi)
            #pragma unroll
            for (int ni = 0; ni < 4; ++ni)
                acc[mi][ni] = __builtin_amdgcn_mfma_f32_16x16x32_bf16(a[mi], bf[ni], acc[mi][ni], 0, 0, 0);
    }
    #pragma unroll
    for (int mi = 0; mi < 2; ++mi)
        #pragma unroll
        for (int r = 0; r < 4; ++r) {
            const int f = mbase + mi * 16 + q * 4 + r;
            const float bs = bias[f];
            #pragma unroll
            for (int ni = 0; ni < 4; ++ni)
                Yb[(size_t)f * LDIM + nbase + ni * 16 + mn] = acc[mi][ni][r] + bs;
        }
}

extern "C" void kernel_launch(void* const* d_in, const int* in_sizes, int n_in,
                              void* d_out, int out_size, void* d_ws, size_t ws_size,
                              hipStream_t stream) {
    const float *x = nullptr, *w_qkv = nullptr, *w_out = nullptr, *b_out = nullptr;
    for (int i = 0; i < n_in; ++i) {
        switch (in_sizes[i]) {
            case 4 * 512 * 2048: x     = (const float*)d_in[i]; break;
            case 512 * 1536:     w_qkv = (const float*)d_in[i]; break;
            case 512 * 512:      w_out = (const float*)d_in[i]; break;
            case 512:            b_out = (const float*)d_in[i]; break;
        }
    }
    float* out = (float*)d_out;                 // [4][512][2048] f32

    const size_t SLAB = (size_t)BATCH * LDIM * 512;      // 4194304 elems
    u16* woT = (u16*)d_ws;                               // [512][512]
    u16* xT  = woT + (size_t)512 * 512;                  // [4][2048][512]
    u16* wT  = xT + SLAB;                                // [1536][512]
    u16* QT  = wT + (size_t)1536 * 512;                  // [32][2048][64]
    u16* KT  = QT + SLAB;                                // [32][2048][64]
    u16* V   = KT + SLAB;                                // [32][64][2048]
    u16* aoT = V + SLAB;                                 // [4][2048][512]

    transpA_k<<<dim3(8, 160), 256, 0, stream>>>(x, w_qkv, w_out, xT, wT, woT);
    qkvgemm_bf16<<<dim3(24, 16, BATCH), 256, 0, stream>>>(xT, wT, QT, KT, V);
    attn_k<<<dim3(32, 64), 128, 0, stream>>>(QT, KT, V, aoT);
    outgemm_d<<<dim3(8, 16, BATCH), 256, 0, stream>>>(aoT, woT, b_out, out);
}

// Round 3
// 238.040 us; speedup vs baseline: 1.2479x; 1.2299x over previous
//
#include <hip/hip_runtime.h>

// B=4, C=512, L=2048, H=8, D=64. f32 inputs, f32 output.
// transpA: one launch: x->xT[b][l][c], w_qkv->wT[f][c], w_out->woT[f][c] (bf16)
// qkvgemm: bf16 MFMA direct-global frags -> *** FRAGMENT-PACKED outputs:
//   QF[bh][i32][ibt][kd][lane][8], KF[bh][j64][jt][kd][lane][8] (kperm absorbed),
//   VF[bh][j64][kj][dt][lane][8]. r2 post-mortem: attn was invariant to 2x
//   occupancy -> shared-resource bound: every attn load was a 16-line scattered
//   dwordx4 (2x L2 over-read, 2x TA cost). Packed layout makes every attn load
//   a coalesced 1KB lane-contiguous stream; register contents are bit-identical
//   to r2 (the permutation moved into qkvgemm's store addressing). ***
// attn: transposed dataflow S^T=K.Q^T, O^T=V.P^T; LDS-free P (lane-local j-slots);
//       2-wave j-split (sum-normalized softmax -> partials add); reg prefetch.
// outgemm: bf16 MFMA direct-global frags, bias, f32 store

#define LDIM 2048
#define CDIM 512
#define BATCH 4

typedef __attribute__((ext_vector_type(8))) short s16x8;
typedef __attribute__((ext_vector_type(4))) float f32x4;
typedef __attribute__((ext_vector_type(4))) unsigned short u16x4;
typedef unsigned int u32;
typedef unsigned short u16;

__device__ __forceinline__ u16 f2b(float f) {
    unsigned u = __float_as_uint(f);
    u += 0x7fffu + ((u >> 16) & 1u);   // RNE
    return (u16)(u >> 16);
}
// pack two floats -> two bf16 (round-half-up) in one u32 (b in high half)
__device__ __forceinline__ u32 pk2(float a, float b) {
    u32 ua = __float_as_uint(a) + 0x8000u;
    u32 ub = __float_as_uint(b) + 0x8000u;
    return __builtin_amdgcn_perm(ub, ua, 0x07060302u);  // {ub.hi16, ua.hi16}
}

// ---------------- unified transpose + f32->bf16 convert ----------------
__global__ __launch_bounds__(256)
void transpA_k(const float* __restrict__ x, const float* __restrict__ wq,
               const float* __restrict__ wo, u16* __restrict__ xT,
               u16* __restrict__ wT, u16* __restrict__ woT)
{
    const int r0 = blockIdx.x * 64;
    const int y  = blockIdx.y;
    const float* in; u16* out; int inLD, c0;
    if (y < 128) {
        const int b = y >> 5, ct = y & 31;
        in = x + (size_t)b * CDIM * LDIM; inLD = LDIM; c0 = ct * 64;
        out = xT + (size_t)b * LDIM * CDIM;
    } else if (y < 152) {
        in = wq; inLD = 1536; c0 = (y - 128) * 64; out = wT;
    } else {
        in = wo; inLD = 512;  c0 = (y - 152) * 64; out = woT;
    }

    __shared__ __align__(16) u16 t[64][80];
    const int tt = threadIdx.x;
    const int lr = tt >> 4, lc = (tt & 15) * 4;
    #pragma unroll
    for (int i = 0; i < 4; ++i) {
        f32x4 v = *(const f32x4*)(in + (size_t)(r0 + lr + i * 16) * inLD + c0 + lc);
        #pragma unroll
        for (int j = 0; j < 4; ++j) t[lc + j][lr + i * 16] = f2b(v[j]);
    }
    __syncthreads();
    const int orow = tt >> 2, ocg = (tt & 3) * 16;
    s16x8 v0 = *(const s16x8*)&t[orow][ocg];
    s16x8 v1 = *(const s16x8*)&t[orow][ocg + 8];
    u16* dst = out + (size_t)(c0 + orow) * CDIM + r0 + ocg;
    *(s16x8*)dst = v0;
    *(s16x8*)(dst + 8) = v1;
}

// ---------------- QKV GEMM -> fragment-packed Q/K/V ----------------
__global__ __launch_bounds__(256)
void qkvgemm_bf16(const u16* __restrict__ xT, const u16* __restrict__ wT,
                  u16* __restrict__ QF, u16* __restrict__ KF, u16* __restrict__ VF)
{
    const int f0 = blockIdx.x * 64;
    const int l0 = blockIdx.y * 128;
    const int b  = blockIdx.z;
    const u16* xTb = xT + (size_t)b * LDIM * CDIM;
    const int t = threadIdx.x, w = t >> 6, lane = t & 63;
    const int mn = lane & 15, q = lane >> 4;
    const bool vpart = (f0 >= 1024);

    const u16 *Abase, *Bbase;
    int mbase, nbase;
    if (!vpart) {
        mbase = f0 + (w >> 1) * 32; nbase = l0 + (w & 1) * 64;
        Abase = wT + (size_t)mbase * CDIM; Bbase = xTb + (size_t)nbase * CDIM;
    } else {
        mbase = l0 + w * 32; nbase = f0;
        Abase = xTb + (size_t)mbase * CDIM; Bbase = wT + (size_t)nbase * CDIM;
    }

    f32x4 acc[2][4] = {};
    #pragma unroll 2
    for (int c0 = 0; c0 < CDIM; c0 += 32) {
        s16x8 a[2], bf[4];
        #pragma unroll
        for (int mi = 0; mi < 2; ++mi)
            a[mi] = *(const s16x8*)(Abase + (size_t)(mi * 16 + mn) * CDIM + c0 + q * 8);
        #pragma unroll
        for (int ni = 0; ni < 4; ++ni)
            bf[ni] = *(const s16x8*)(Bbase + (size_t)(ni * 16 + mn) * CDIM + c0 + q * 8);
        #pragma unroll
        for (int mi = 0; mi < 2; ++mi)
            #pragma unroll
            for (int ni = 0; ni < 4; ++ni)
                acc[mi][ni] = __builtin_amdgcn_mfma_f32_16x16x32_bf16(a[mi], bf[ni], acc[mi][ni], 0, 0, 0);
    }

    if (!vpart) {
        const int part = f0 >> 9;
        const float sc2 = (part == 0) ? 0.18033688f : 1.0f;  // 0.125*log2(e)
        u16* Tout = (part == 0) ? QF : KF;
        #pragma unroll
        for (int mi = 0; mi < 2; ++mi) {
            const int fg0 = mbase + mi * 16;
            const int h = (fg0 >> 6) & 7;
            const int d0 = (fg0 & 63) + q * 4;          // 4-aligned d base
            const int kd = d0 >> 5, qq = (d0 >> 3) & 3, e0 = d0 & 7;
            u16* T = Tout + (size_t)(b * 8 + h) * LDIM * 64;
            #pragma unroll
            for (int ni = 0; ni < 4; ++ni) {
                const int lg = nbase + ni * 16 + mn;     // L index
                size_t addr;
                if (part == 0) {                         // QF[i32][ibt][kd][lane][8]
                    const int i32 = lg >> 5, ibt = (lg >> 4) & 1, mnq = lg & 15;
                    addr = (size_t)(((i32 * 2 + ibt) * 2 + kd) * 512 + (qq * 16 + mnq) * 8 + e0);
                } else {                                 // KF[j64][jt][kd][lane][8], kperm absorbed
                    const int j64 = lg >> 6, r6 = lg & 63;
                    const int jt  = ((r6 >> 2) & 1) * 2 + (r6 >> 5);
                    const int mnk = ((r6 >> 3) & 3) * 4 + (r6 & 3);
                    addr = (size_t)(((j64 * 4 + jt) * 2 + kd) * 512 + (qq * 16 + mnk) * 8 + e0);
                }
                u16x4 pk;
                #pragma unroll
                for (int r = 0; r < 4; ++r) pk[r] = f2b(acc[mi][ni][r] * sc2);
                *(u16x4*)(T + addr) = pk;
            }
        }
    } else {
        #pragma unroll
        for (int ni = 0; ni < 4; ++ni) {
            const int fg = nbase + ni * 16 + mn;
            const int h = (fg >> 6) & 7;
            const int d = fg & 63;
            const int dt = d >> 4, mnv = d & 15;
            u16* Vb = VF + (size_t)(b * 8 + h) * LDIM * 64;
            #pragma unroll
            for (int mi = 0; mi < 2; ++mi) {
                const int lg0 = mbase + mi * 16 + q * 4;    // 4-aligned j base
                const int j64 = lg0 >> 6, j6 = lg0 & 63;
                const int kj = j6 >> 5, qq = (j6 >> 3) & 3, e0 = j6 & 7;
                const size_t addr = (size_t)(((j64 * 2 + kj) * 4 + dt) * 512 + (qq * 16 + mnv) * 8 + e0);
                u16x4 pk;
                #pragma unroll
                for (int r = 0; r < 4; ++r) pk[r] = f2b(acc[mi][ni][r]);
                *(u16x4*)(Vb + addr) = pk;
            }
        }
    }
}

// ---------------- Flash attention: packed frags, LDS-free P, 2-wave j-split -----
// grid (x=bh 32, y=64), 128 threads (2 waves). All loads lane-contiguous 1KB.
__global__ __launch_bounds__(128)
void attn_k(const u16* __restrict__ QF, const u16* __restrict__ KF,
            const u16* __restrict__ VF, u16* __restrict__ aoT)
{
    const int bh = blockIdx.x;
    const int b = bh >> 3, h = bh & 7;
    const u16* Qh = QF + (size_t)bh * LDIM * 64;
    const u16* Kh = KF + (size_t)bh * LDIM * 64;
    const u16* Vh = VF + (size_t)bh * LDIM * 64;

    __shared__ __align__(16) float o_sh[32][68];   // +4 pad
    __shared__ float lp_sh[32];

    const int tid = threadIdx.x;
    const int wv = tid >> 6;
    const int lane = tid & 63;
    const int mn = lane & 15, q = lane >> 4;
    const int i32 = blockIdx.y;
    const int iw = i32 * 32;
    const int NT = LDIM / 64;            // 32 j-tiles
    const int TH = NT / 2;               // 16 per wave
    const int tbase = wv * TH;

    s16x8 aq[2][2];
    #pragma unroll
    for (int ibt = 0; ibt < 2; ++ibt)
        #pragma unroll
        for (int kd = 0; kd < 2; ++kd)
            aq[ibt][kd] = *(const s16x8*)(Qh + (size_t)(((i32 * 2 + ibt) * 2 + kd) * 512) + lane * 8);

    f32x4 o_acc[2][4] = {};
    float lp[2] = {0.f, 0.f};

    // preload this wave's tile-0 K/V fragments (fully coalesced)
    s16x8 kc[2][4], vc[2][4];
    {
        const u16* Kt = Kh + (size_t)tbase * 4096;
        const u16* Vt = Vh + (size_t)tbase * 4096;
        #pragma unroll
        for (int kd = 0; kd < 2; ++kd)
            #pragma unroll
            for (int jt = 0; jt < 4; ++jt)
                kc[kd][jt] = *(const s16x8*)(Kt + ((jt * 2 + kd) << 9) + (lane << 3));
        #pragma unroll
        for (int kj = 0; kj < 2; ++kj)
            #pragma unroll
            for (int dt = 0; dt < 4; ++dt)
                vc[kj][dt] = *(const s16x8*)(Vt + ((kj * 4 + dt) << 9) + (lane << 3));
    }

    #pragma unroll 2
    for (int jj = 0; jj < TH; ++jj) {
        const int tn = tbase + ((jj + 1) & (TH - 1));   // last iter wraps (L2-hot)

        // issue next tile's loads FIRST (one full iteration of latency hiding)
        s16x8 kn[2][4], vn[2][4];
        {
            const u16* Kt = Kh + (size_t)tn * 4096;
            const u16* Vt = Vh + (size_t)tn * 4096;
            #pragma unroll
            for (int kd = 0; kd < 2; ++kd)
                #pragma unroll
                for (int jt = 0; jt < 4; ++jt)
                    kn[kd][jt] = *(const s16x8*)(Kt + ((jt * 2 + kd) << 9) + (lane << 3));
            #pragma unroll
            for (int kj = 0; kj < 2; ++kj)
                #pragma unroll
                for (int dt = 0; dt < 4; ++dt)
                    vn[kj][dt] = *(const s16x8*)(Vt + ((kj * 4 + dt) << 9) + (lane << 3));
        }

        // S^T = K.Q^T on current K
        f32x4 s[2][4] = {};
        #pragma unroll
        for (int kd = 0; kd < 2; ++kd)
            #pragma unroll
            for (int jt = 0; jt < 4; ++jt) {
                s[0][jt] = __builtin_amdgcn_mfma_f32_16x16x32_bf16(kc[kd][jt], aq[0][kd], s[0][jt], 0, 0, 0);
                s[1][jt] = __builtin_amdgcn_mfma_f32_16x16x32_bf16(kc[kd][jt], aq[1][kd], s[1][jt], 0, 0, 0);
            }

        // p = 2^s; build PV B-fragments fully in-register (lane-local j-slots).
        #pragma unroll
        for (int kj = 0; kj < 2; ++kj) {
            s16x8 ap[2];
            #pragma unroll
            for (int ibt = 0; ibt < 2; ++ibt) {
                float pa0 = __builtin_amdgcn_exp2f(s[ibt][kj][0]);
                float pa1 = __builtin_amdgcn_exp2f(s[ibt][kj][1]);
                float pa2 = __builtin_amdgcn_exp2f(s[ibt][kj][2]);
                float pa3 = __builtin_amdgcn_exp2f(s[ibt][kj][3]);
                float pb0 = __builtin_amdgcn_exp2f(s[ibt][kj + 2][0]);
                float pb1 = __builtin_amdgcn_exp2f(s[ibt][kj + 2][1]);
                float pb2 = __builtin_amdgcn_exp2f(s[ibt][kj + 2][2]);
                float pb3 = __builtin_amdgcn_exp2f(s[ibt][kj + 2][3]);
                lp[ibt] += ((pa0 + pa1) + (pa2 + pa3)) + ((pb0 + pb1) + (pb2 + pb3));
                union { s16x8 v; u32 w[4]; } u;
                u.w[0] = pk2(pa0, pa1);
                u.w[1] = pk2(pa2, pa3);
                u.w[2] = pk2(pb0, pb1);
                u.w[3] = pk2(pb2, pb3);
                ap[ibt] = u.v;
            }
            #pragma unroll
            for (int dt = 0; dt < 4; ++dt) {
                o_acc[0][dt] = __builtin_amdgcn_mfma_f32_16x16x32_bf16(vc[kj][dt], ap[0], o_acc[0][dt], 0, 0, 0);
                o_acc[1][dt] = __builtin_amdgcn_mfma_f32_16x16x32_bf16(vc[kj][dt], ap[1], o_acc[1][dt], 0, 0, 0);
            }
        }

        // rotate prefetched registers
        #pragma unroll
        for (int kd = 0; kd < 2; ++kd)
            #pragma unroll
            for (int jt = 0; jt < 4; ++jt)
                kc[kd][jt] = kn[kd][jt];
        #pragma unroll
        for (int kj = 0; kj < 2; ++kj)
            #pragma unroll
            for (int dt = 0; dt < 4; ++dt)
                vc[kj][dt] = vn[kj][dt];
    }

    #pragma unroll
    for (int ibt = 0; ibt < 2; ++ibt) {
        lp[ibt] += __shfl_xor(lp[ibt], 16);
        lp[ibt] += __shfl_xor(lp[ibt], 32);
    }

    // combine the two waves' j-partials: plain addition (sum-normalized softmax)
    if (wv == 1) {
        #pragma unroll
        for (int ibt = 0; ibt < 2; ++ibt) {
            #pragma unroll
            for (int dt = 0; dt < 4; ++dt)
                *(f32x4*)&o_sh[ibt * 16 + mn][dt * 16 + q * 4] = o_acc[ibt][dt];
            if (q == 0) lp_sh[ibt * 16 + mn] = lp[ibt];
        }
    }
    __syncthreads();
    if (wv == 0) {
        #pragma unroll
        for (int ibt = 0; ibt < 2; ++ibt) {
            const float rinv = 1.0f / (lp[ibt] + lp_sh[ibt * 16 + mn]);
            u16* dst = aoT + ((size_t)b * LDIM + iw + ibt * 16 + mn) * 512 + h * 64 + q * 4;
            #pragma unroll
            for (int dt = 0; dt < 4; ++dt) {
                f32x4 os = *(const f32x4*)&o_sh[ibt * 16 + mn][dt * 16 + q * 4];
                u16x4 pk;
                #pragma unroll
                for (int r = 0; r < 4; ++r)
                    pk[r] = f2b((o_acc[ibt][dt][r] + os[r]) * rinv);
                *(u16x4*)(dst + dt * 16) = pk;
            }
        }
    }
}

// ---------------- Output GEMM (unchanged) ----------------
__global__ __launch_bounds__(256)
void outgemm_d(const u16* __restrict__ aoT, const u16* __restrict__ woT,
               const float* __restrict__ bias, float* __restrict__ Y)
{
    const int f0 = blockIdx.x * 64;
    const int l0 = blockIdx.y * 128;
    const int b  = blockIdx.z;
    const int t = threadIdx.x, w = t >> 6, lane = t & 63;
    const int mn = lane & 15, q = lane >> 4;
    const int mbase = f0 + (w >> 1) * 32;
    const int nbase = l0 + (w & 1) * 64;
    const u16* Abase = woT + (size_t)mbase * CDIM;
    const u16* Bbase = aoT + ((size_t)b * LDIM + nbase) * CDIM;
    float* Yb = Y + (size_t)b * CDIM * LDIM;

    f32x4 acc[2][4] = {};
    #pragma unroll 2
    for (int c0 = 0; c0 < CDIM; c0 += 32) {
        s16x8 a[2], bf[4];
        #pragma unroll
        for (int mi = 0; mi < 2; ++mi)
            a[mi] = *(const s16x8*)(Abase + (size_t)(mi * 16 + mn) * CDIM + c0 + q * 8);
        #pragma unroll
        for (int ni = 0; ni < 4; ++ni)
            bf[ni] = *(const s16x8*)(Bbase + (size_t)(ni * 16 + mn) * CDIM + c0 + q * 8);
        #pragma unroll
        for (int mi = 0; mi < 2; ++mi)
            #pragma unroll
            for (int ni = 0; ni < 4; ++ni)
                acc[mi][ni] = __builtin_amdgcn_mfma_f32_16x16x32_bf16(a[mi], bf[ni], acc[mi][ni], 0, 0, 0);
    }
    #pragma unroll
    for (int mi = 0; mi < 2; ++mi)
        #pragma unroll
        for (int r = 0; r < 4; ++r) {
            const int f = mbase + mi * 16 + q * 4 + r;
            const float bs = bias[f];
            #pragma unroll
            for (int ni = 0; ni < 4; ++ni)
                Yb[(size_t)f * LDIM + nbase + ni * 16 + mn] = acc[mi][ni][r] + bs;
        }
}

extern "C" void kernel_launch(void* const* d_in, const int* in_sizes, int n_in,
                              void* d_out, int out_size, void* d_ws, size_t ws_size,
                              hipStream_t stream) {
    const float *x = nullptr, *w_qkv = nullptr, *w_out = nullptr, *b_out = nullptr;
    for (int i = 0; i < n_in; ++i) {
        switch (in_sizes[i]) {
            case 4 * 512 * 2048: x     = (const float*)d_in[i]; break;
            case 512 * 1536:     w_qkv = (const float*)d_in[i]; break;
            case 512 * 512:      w_out = (const float*)d_in[i]; break;
            case 512:            b_out = (const float*)d_in[i]; break;
        }
    }
    float* out = (float*)d_out;                 // [4][512][2048] f32

    const size_t SLAB = (size_t)BATCH * LDIM * 512;      // 4194304 elems
    u16* woT = (u16*)d_ws;                               // [512][512]
    u16* xT  = woT + (size_t)512 * 512;                  // [4][2048][512]
    u16* wT  = xT + SLAB;                                // [1536][512]
    u16* QF  = wT + (size_t)1536 * 512;                  // [32][2048*64] packed
    u16* KF  = QF + SLAB;                                // [32][2048*64] packed
    u16* VF  = KF + SLAB;                                // [32][2048*64] packed
    u16* aoT = VF + SLAB;                                // [4][2048][512]

    transpA_k<<<dim3(8, 160), 256, 0, stream>>>(x, w_qkv, w_out, xT, wT, woT);
    qkvgemm_bf16<<<dim3(24, 16, BATCH), 256, 0, stream>>>(xT, wT, QF, KF, VF);
    attn_k<<<dim3(32, 64), 128, 0, stream>>>(QF, KF, VF, aoT);
    outgemm_d<<<dim3(8, 16, BATCH), 256, 0, stream>>>(aoT, woT, b_out, out);
}

// Round 4
// 190.061 us; speedup vs baseline: 1.5629x; 1.2524x over previous
//
#include <hip/hip_runtime.h>

// B=4, C=512, L=2048, H=8, D=64. f32 inputs, f32 output.
// *** UNIVERSAL FRAGMENT-PACKED LAYOUTS (r4): every MFMA operand everywhere is
// stored in chunk order [rtile=row/16][cstep=col/32][lane][8] so that every
// operand load in qkvgemm/outgemm/attn is one lane-contiguous 1KB read
// (8 cache lines) instead of a 16-row scattered dwordx4 (16 lines). r3 proved
// this lever on attn (139->89us); r4 applies it to xT/wT/woT (transpA stores),
// qkvgemm loads, aoT (attn epilogue store -> outgemm B loads). Register
// contents are bit-identical to r3 throughout. ***
// transpA: one launch: x->XP, w_qkv->WP, w_out->WOP (bf16, packed)
// qkvgemm: packed-chunk loads -> QF/KF/VF (attn fragment order, kperm absorbed)
// attn: S^T=K.Q^T, O^T=V.P^T; LDS-free P; 2-wave j-split; reg prefetch; packed aoT
// outgemm: packed-chunk loads, bias, f32 store

#define LDIM 2048
#define CDIM 512
#define BATCH 4

typedef __attribute__((ext_vector_type(8))) short s16x8;
typedef __attribute__((ext_vector_type(4))) float f32x4;
typedef __attribute__((ext_vector_type(4))) unsigned short u16x4;
typedef unsigned int u32;
typedef unsigned short u16;

__device__ __forceinline__ u16 f2b(float f) {
    unsigned u = __float_as_uint(f);
    u += 0x7fffu + ((u >> 16) & 1u);   // RNE
    return (u16)(u >> 16);
}
// pack two floats -> two bf16 (round-half-up) in one u32 (b in high half)
__device__ __forceinline__ u32 pk2(float a, float b) {
    u32 ua = __float_as_uint(a) + 0x8000u;
    u32 ub = __float_as_uint(b) + 0x8000u;
    return __builtin_amdgcn_perm(ub, ua, 0x07060302u);  // {ub.hi16, ua.hi16}
}

// ---------------- unified transpose + f32->bf16 convert -> packed chunks -------
// chunk(row,col): elem(rtile*16+mn, cstep*32+q*8+e) at ((rtile*16+cstep)*64+lane)*8+e
__global__ __launch_bounds__(256)
void transpA_k(const float* __restrict__ x, const float* __restrict__ wq,
               const float* __restrict__ wo, u16* __restrict__ XP,
               u16* __restrict__ WP, u16* __restrict__ WOP)
{
    const int r0 = blockIdx.x * 64;
    const int y  = blockIdx.y;
    const float* in; u16* out; int inLD, c0;
    if (y < 128) {
        const int b = y >> 5, ct = y & 31;
        in = x + (size_t)b * CDIM * LDIM; inLD = LDIM; c0 = ct * 64;
        out = XP + (size_t)b * LDIM * CDIM;
    } else if (y < 152) {
        in = wq; inLD = 1536; c0 = (y - 128) * 64; out = WP;
    } else {
        in = wo; inLD = 512;  c0 = (y - 152) * 64; out = WOP;
    }

    __shared__ __align__(16) u16 t[64][80];
    const int tt = threadIdx.x;
    const int lr = tt >> 4, lc = (tt & 15) * 4;
    #pragma unroll
    for (int i = 0; i < 4; ++i) {
        f32x4 v = *(const f32x4*)(in + (size_t)(r0 + lr + i * 16) * inLD + c0 + lc);
        #pragma unroll
        for (int j = 0; j < 4; ++j) t[lc + j][lr + i * 16] = f2b(v[j]);
    }
    __syncthreads();
    const int orow = tt >> 2, ocg = (tt & 3) * 16;
    s16x8 v0 = *(const s16x8*)&t[orow][ocg];
    s16x8 v1 = *(const s16x8*)&t[orow][ocg + 8];
    const int row   = c0 + orow;            // l (or f) index
    const int rtile = row >> 4, rr = row & 15;
    const int cstep = (r0 + ocg) >> 5;      // 32-col step within CDIM-like axis
    const int qb    = (ocg >> 3) & 3;       // 0 or 2
    u16* dst = out + ((size_t)(rtile * 16 + cstep) * 64 + qb * 16 + rr) * 8;
    *(s16x8*)dst = v0;                      // q = qb   half
    *(s16x8*)(dst + 128) = v1;              // q = qb+1 half
}

// ---------------- QKV GEMM: packed-chunk loads -> fragment-packed Q/K/V --------
__global__ __launch_bounds__(256)
void qkvgemm_bf16(const u16* __restrict__ XP, const u16* __restrict__ WP,
                  u16* __restrict__ QF, u16* __restrict__ KF, u16* __restrict__ VF)
{
    const int f0 = blockIdx.x * 64;
    const int l0 = blockIdx.y * 128;
    const int b  = blockIdx.z;
    const u16* xTb = XP + (size_t)b * LDIM * CDIM;
    const int t = threadIdx.x, w = t >> 6, lane = t & 63;
    const int mn = lane & 15, q = lane >> 4;
    const bool vpart = (f0 >= 1024);

    const u16 *Abase, *Bbase;
    int mbase, nbase;
    if (!vpart) {
        mbase = f0 + (w >> 1) * 32; nbase = l0 + (w & 1) * 64;
        Abase = WP + (size_t)mbase * CDIM; Bbase = xTb + (size_t)nbase * CDIM;
    } else {
        mbase = l0 + w * 32; nbase = f0;
        Abase = xTb + (size_t)mbase * CDIM; Bbase = WP + (size_t)nbase * CDIM;
    }

    f32x4 acc[2][4] = {};
    #pragma unroll 2
    for (int c0 = 0; c0 < CDIM; c0 += 32) {
        s16x8 a[2], bf[4];
        #pragma unroll
        for (int mi = 0; mi < 2; ++mi)
            a[mi] = *(const s16x8*)(Abase + mi * 16 * CDIM + c0 * 16 + lane * 8);
        #pragma unroll
        for (int ni = 0; ni < 4; ++ni)
            bf[ni] = *(const s16x8*)(Bbase + ni * 16 * CDIM + c0 * 16 + lane * 8);
        #pragma unroll
        for (int mi = 0; mi < 2; ++mi)
            #pragma unroll
            for (int ni = 0; ni < 4; ++ni)
                acc[mi][ni] = __builtin_amdgcn_mfma_f32_16x16x32_bf16(a[mi], bf[ni], acc[mi][ni], 0, 0, 0);
    }

    if (!vpart) {
        const int part = f0 >> 9;
        const float sc2 = (part == 0) ? 0.18033688f : 1.0f;  // 0.125*log2(e)
        u16* Tout = (part == 0) ? QF : KF;
        #pragma unroll
        for (int mi = 0; mi < 2; ++mi) {
            const int fg0 = mbase + mi * 16;
            const int h = (fg0 >> 6) & 7;
            const int d0 = (fg0 & 63) + q * 4;          // 4-aligned d base
            const int kd = d0 >> 5, qq = (d0 >> 3) & 3, e0 = d0 & 7;
            u16* T = Tout + (size_t)(b * 8 + h) * LDIM * 64;
            #pragma unroll
            for (int ni = 0; ni < 4; ++ni) {
                const int lg = nbase + ni * 16 + mn;     // L index
                size_t addr;
                if (part == 0) {                         // QF[i32][ibt][kd][lane][8]
                    const int i32 = lg >> 5, ibt = (lg >> 4) & 1, mnq = lg & 15;
                    addr = (size_t)(((i32 * 2 + ibt) * 2 + kd) * 512 + (qq * 16 + mnq) * 8 + e0);
                } else {                                 // KF[j64][jt][kd][lane][8], kperm absorbed
                    const int j64 = lg >> 6, r6 = lg & 63;
                    const int jt  = ((r6 >> 2) & 1) * 2 + (r6 >> 5);
                    const int mnk = ((r6 >> 3) & 3) * 4 + (r6 & 3);
                    addr = (size_t)(((j64 * 4 + jt) * 2 + kd) * 512 + (qq * 16 + mnk) * 8 + e0);
                }
                u16x4 pk;
                #pragma unroll
                for (int r = 0; r < 4; ++r) pk[r] = f2b(acc[mi][ni][r] * sc2);
                *(u16x4*)(T + addr) = pk;
            }
        }
    } else {
        #pragma unroll
        for (int ni = 0; ni < 4; ++ni) {
            const int fg = nbase + ni * 16 + mn;
            const int h = (fg >> 6) & 7;
            const int d = fg & 63;
            const int dt = d >> 4, mnv = d & 15;
            u16* Vb = VF + (size_t)(b * 8 + h) * LDIM * 64;
            #pragma unroll
            for (int mi = 0; mi < 2; ++mi) {
                const int lg0 = mbase + mi * 16 + q * 4;    // 4-aligned j base
                const int j64 = lg0 >> 6, j6 = lg0 & 63;
                const int kj = j6 >> 5, qq = (j6 >> 3) & 3, e0 = j6 & 7;
                const size_t addr = (size_t)(((j64 * 2 + kj) * 4 + dt) * 512 + (qq * 16 + mnv) * 8 + e0);
                u16x4 pk;
                #pragma unroll
                for (int r = 0; r < 4; ++r) pk[r] = f2b(acc[mi][ni][r]);
                *(u16x4*)(Vb + addr) = pk;
            }
        }
    }
}

// ---------------- Flash attention: packed frags, LDS-free P, 2-wave j-split -----
// grid (x=bh 32, y=64), 128 threads (2 waves). All loads lane-contiguous 1KB.
__global__ __launch_bounds__(128)
void attn_k(const u16* __restrict__ QF, const u16* __restrict__ KF,
            const u16* __restrict__ VF, u16* __restrict__ aoP)
{
    const int bh = blockIdx.x;
    const int b = bh >> 3, h = bh & 7;
    const u16* Qh = QF + (size_t)bh * LDIM * 64;
    const u16* Kh = KF + (size_t)bh * LDIM * 64;
    const u16* Vh = VF + (size_t)bh * LDIM * 64;

    __shared__ __align__(16) float o_sh[32][68];   // +4 pad
    __shared__ float lp_sh[32];

    const int tid = threadIdx.x;
    const int wv = tid >> 6;
    const int lane = tid & 63;
    const int mn = lane & 15, q = lane >> 4;
    const int i32 = blockIdx.y;
    const int iw = i32 * 32;
    const int NT = LDIM / 64;            // 32 j-tiles
    const int TH = NT / 2;               // 16 per wave
    const int tbase = wv * TH;

    s16x8 aq[2][2];
    #pragma unroll
    for (int ibt = 0; ibt < 2; ++ibt)
        #pragma unroll
        for (int kd = 0; kd < 2; ++kd)
            aq[ibt][kd] = *(const s16x8*)(Qh + (size_t)(((i32 * 2 + ibt) * 2 + kd) * 512) + lane * 8);

    f32x4 o_acc[2][4] = {};
    float lp[2] = {0.f, 0.f};

    // preload this wave's tile-0 K/V fragments (fully coalesced)
    s16x8 kc[2][4], vc[2][4];
    {
        const u16* Kt = Kh + (size_t)tbase * 4096;
        const u16* Vt = Vh + (size_t)tbase * 4096;
        #pragma unroll
        for (int kd = 0; kd < 2; ++kd)
            #pragma unroll
            for (int jt = 0; jt < 4; ++jt)
                kc[kd][jt] = *(const s16x8*)(Kt + ((jt * 2 + kd) << 9) + (lane << 3));
        #pragma unroll
        for (int kj = 0; kj < 2; ++kj)
            #pragma unroll
            for (int dt = 0; dt < 4; ++dt)
                vc[kj][dt] = *(const s16x8*)(Vt + ((kj * 4 + dt) << 9) + (lane << 3));
    }

    #pragma unroll 2
    for (int jj = 0; jj < TH; ++jj) {
        const int tn = tbase + ((jj + 1) & (TH - 1));   // last iter wraps (L2-hot)

        // issue next tile's loads FIRST (one full iteration of latency hiding)
        s16x8 kn[2][4], vn[2][4];
        {
            const u16* Kt = Kh + (size_t)tn * 4096;
            const u16* Vt = Vh + (size_t)tn * 4096;
            #pragma unroll
            for (int kd = 0; kd < 2; ++kd)
                #pragma unroll
                for (int jt = 0; jt < 4; ++jt)
                    kn[kd][jt] = *(const s16x8*)(Kt + ((jt * 2 + kd) << 9) + (lane << 3));
            #pragma unroll
            for (int kj = 0; kj < 2; ++kj)
                #pragma unroll
                for (int dt = 0; dt < 4; ++dt)
                    vn[kj][dt] = *(const s16x8*)(Vt + ((kj * 4 + dt) << 9) + (lane << 3));
        }

        // S^T = K.Q^T on current K
        f32x4 s[2][4] = {};
        #pragma unroll
        for (int kd = 0; kd < 2; ++kd)
            #pragma unroll
            for (int jt = 0; jt < 4; ++jt) {
                s[0][jt] = __builtin_amdgcn_mfma_f32_16x16x32_bf16(kc[kd][jt], aq[0][kd], s[0][jt], 0, 0, 0);
                s[1][jt] = __builtin_amdgcn_mfma_f32_16x16x32_bf16(kc[kd][jt], aq[1][kd], s[1][jt], 0, 0, 0);
            }

        // p = 2^s; build PV B-fragments fully in-register (lane-local j-slots).
        #pragma unroll
        for (int kj = 0; kj < 2; ++kj) {
            s16x8 ap[2];
            #pragma unroll
            for (int ibt = 0; ibt < 2; ++ibt) {
                float pa0 = __builtin_amdgcn_exp2f(s[ibt][kj][0]);
                float pa1 = __builtin_amdgcn_exp2f(s[ibt][kj][1]);
                float pa2 = __builtin_amdgcn_exp2f(s[ibt][kj][2]);
                float pa3 = __builtin_amdgcn_exp2f(s[ibt][kj][3]);
                float pb0 = __builtin_amdgcn_exp2f(s[ibt][kj + 2][0]);
                float pb1 = __builtin_amdgcn_exp2f(s[ibt][kj + 2][1]);
                float pb2 = __builtin_amdgcn_exp2f(s[ibt][kj + 2][2]);
                float pb3 = __builtin_amdgcn_exp2f(s[ibt][kj + 2][3]);
                lp[ibt] += ((pa0 + pa1) + (pa2 + pa3)) + ((pb0 + pb1) + (pb2 + pb3));
                union { s16x8 v; u32 w[4]; } u;
                u.w[0] = pk2(pa0, pa1);
                u.w[1] = pk2(pa2, pa3);
                u.w[2] = pk2(pb0, pb1);
                u.w[3] = pk2(pb2, pb3);
                ap[ibt] = u.v;
            }
            #pragma unroll
            for (int dt = 0; dt < 4; ++dt) {
                o_acc[0][dt] = __builtin_amdgcn_mfma_f32_16x16x32_bf16(vc[kj][dt], ap[0], o_acc[0][dt], 0, 0, 0);
                o_acc[1][dt] = __builtin_amdgcn_mfma_f32_16x16x32_bf16(vc[kj][dt], ap[1], o_acc[1][dt], 0, 0, 0);
            }
        }

        // rotate prefetched registers
        #pragma unroll
        for (int kd = 0; kd < 2; ++kd)
            #pragma unroll
            for (int jt = 0; jt < 4; ++jt)
                kc[kd][jt] = kn[kd][jt];
        #pragma unroll
        for (int kj = 0; kj < 2; ++kj)
            #pragma unroll
            for (int dt = 0; dt < 4; ++dt)
                vc[kj][dt] = vn[kj][dt];
    }

    #pragma unroll
    for (int ibt = 0; ibt < 2; ++ibt) {
        lp[ibt] += __shfl_xor(lp[ibt], 16);
        lp[ibt] += __shfl_xor(lp[ibt], 32);
    }

    // combine the two waves' j-partials: plain addition (sum-normalized softmax)
    if (wv == 1) {
        #pragma unroll
        for (int ibt = 0; ibt < 2; ++ibt) {
            #pragma unroll
            for (int dt = 0; dt < 4; ++dt)
                *(f32x4*)&o_sh[ibt * 16 + mn][dt * 16 + q * 4] = o_acc[ibt][dt];
            if (q == 0) lp_sh[ibt * 16 + mn] = lp[ibt];
        }
    }
    __syncthreads();
    if (wv == 0) {
        u16* Ab = aoP + (size_t)b * LDIM * 512;
        #pragma unroll
        for (int ibt = 0; ibt < 2; ++ibt) {
            const float rinv = 1.0f / (lp[ibt] + lp_sh[ibt * 16 + mn]);
            const int ltile = (iw >> 4) + ibt;
            #pragma unroll
            for (int dt = 0; dt < 4; ++dt) {
                f32x4 os = *(const f32x4*)&o_sh[ibt * 16 + mn][dt * 16 + q * 4];
                u16x4 pk;
                #pragma unroll
                for (int r = 0; r < 4; ++r)
                    pk[r] = f2b((o_acc[ibt][dt][r] + os[r]) * rinv);
                // packed-chunk store: col = h*64 + dt*16 + q*4 + r
                const int cstep = h * 2 + (dt >> 1);
                const int lanep = ((dt & 1) * 2 + (q >> 1)) * 16 + mn;
                u16* dst = Ab + ((size_t)(ltile * 16 + cstep) * 64 + lanep) * 8 + (q & 1) * 4;
                *(u16x4*)dst = pk;
            }
        }
    }
}

// ---------------- Output GEMM: packed-chunk loads ----------------
__global__ __launch_bounds__(256)
void outgemm_d(const u16* __restrict__ aoP, const u16* __restrict__ WOP,
               const float* __restrict__ bias, float* __restrict__ Y)
{
    const int f0 = blockIdx.x * 64;
    const int l0 = blockIdx.y * 128;
    const int b  = blockIdx.z;
    const int t = threadIdx.x, w = t >> 6, lane = t & 63;
    const int mn = lane & 15, q = lane >> 4;
    const int mbase = f0 + (w >> 1) * 32;
    const int nbase = l0 + (w & 1) * 64;
    const u16* Abase = WOP + (size_t)mbase * CDIM;
    const u16* Bbase = aoP + ((size_t)b * LDIM + nbase) * CDIM;
    float* Yb = Y + (size_t)b * CDIM * LDIM;

    f32x4 acc[2][4] = {};
    #pragma unroll 2
    for (int c0 = 0; c0 < CDIM; c0 += 32) {
        s16x8 a[2], bf[4];
        #pragma unroll
        for (int mi = 0; mi < 2; ++mi)
            a[mi] = *(const s16x8*)(Abase + mi * 16 * CDIM + c0 * 16 + lane * 8);
        #pragma unroll
        for (int ni = 0; ni < 4; ++ni)
            bf[ni] = *(const s16x8*)(Bbase + ni * 16 * CDIM + c0 * 16 + lane * 8);
        #pragma unroll
        for (int mi = 0; mi < 2; ++mi)
            #pragma unroll
            for (int ni = 0; ni < 4; ++ni)
                acc[mi][ni] = __builtin_amdgcn_mfma_f32_16x16x32_bf16(a[mi], bf[ni], acc[mi][ni], 0, 0, 0);
    }
    #pragma unroll
    for (int mi = 0; mi < 2; ++mi)
        #pragma unroll
        for (int r = 0; r < 4; ++r) {
            const int f = mbase + mi * 16 + q * 4 + r;
            const float bs = bias[f];
            #pragma unroll
            for (int ni = 0; ni < 4; ++ni)
                Yb[(size_t)f * LDIM + nbase + ni * 16 + mn] = acc[mi][ni][r] + bs;
        }
}

extern "C" void kernel_launch(void* const* d_in, const int* in_sizes, int n_in,
                              void* d_out, int out_size, void* d_ws, size_t ws_size,
                              hipStream_t stream) {
    const float *x = nullptr, *w_qkv = nullptr, *w_out = nullptr, *b_out = nullptr;
    for (int i = 0; i < n_in; ++i) {
        switch (in_sizes[i]) {
            case 4 * 512 * 2048: x     = (const float*)d_in[i]; break;
            case 512 * 1536:     w_qkv = (const float*)d_in[i]; break;
            case 512 * 512:      w_out = (const float*)d_in[i]; break;
            case 512:            b_out = (const float*)d_in[i]; break;
        }
    }
    float* out = (float*)d_out;                 // [4][512][2048] f32

    const size_t SLAB = (size_t)BATCH * LDIM * 512;      // 4194304 elems
    u16* WOP = (u16*)d_ws;                               // [512 rows][512] packed
    u16* XP  = WOP + (size_t)512 * 512;                  // [4][2048 rows][512] packed
    u16* WP  = XP + SLAB;                                // [1536 rows][512] packed
    u16* QF  = WP + (size_t)1536 * 512;                  // [32][2048*64] attn-packed
    u16* KF  = QF + SLAB;                                // [32][2048*64] attn-packed
    u16* VF  = KF + SLAB;                                // [32][2048*64] attn-packed
    u16* aoP = VF + SLAB;                                // [4][2048 rows][512] packed

    transpA_k<<<dim3(8, 160), 256, 0, stream>>>(x, w_qkv, w_out, XP, WP, WOP);
    qkvgemm_bf16<<<dim3(24, 16, BATCH), 256, 0, stream>>>(XP, WP, QF, KF, VF);
    attn_k<<<dim3(32, 64), 128, 0, stream>>>(QF, KF, VF, aoP);
    outgemm_d<<<dim3(8, 16, BATCH), 256, 0, stream>>>(aoP, WOP, b_out, out);
}

// Round 5
// 176.652 us; speedup vs baseline: 1.6816x; 1.0759x over previous
//
#include <hip/hip_runtime.h>

// B=4, C=512, L=2048, H=8, D=64. f32 inputs, f32 output.
// Universal fragment-packed layouts (r4): every MFMA operand load everywhere is
// one lane-contiguous 1KB read. r5: *** attn i-tile 32->64 rows per block:
// r4 counters showed all pipes ~15-30% busy -> traffic/latency bound on K/V
// re-reads (1.05GB L1 traffic, ~26us floor). 4 ibt sub-tiles per wave halves
// K/V traffic per FLOP and doubles per-iter independent work so the 1-iter
// register prefetch fully covers L2 latency. V prefetch staggered after QK
// phase to cap VGPR peak. ***
// transpA: x->XP, w_qkv->WP, w_out->WOP (bf16, packed chunks)
// qkvgemm: packed-chunk loads -> QF/KF/VF (attn fragment order, kperm absorbed)
// attn: S^T=K.Q^T, O^T=V.P^T; LDS-free P; 2-wave j-split; 64 i-rows/block
// outgemm: packed-chunk loads, bias, f32 store

#define LDIM 2048
#define CDIM 512
#define BATCH 4

typedef __attribute__((ext_vector_type(8))) short s16x8;
typedef __attribute__((ext_vector_type(4))) float f32x4;
typedef __attribute__((ext_vector_type(4))) unsigned short u16x4;
typedef unsigned int u32;
typedef unsigned short u16;

__device__ __forceinline__ u16 f2b(float f) {
    unsigned u = __float_as_uint(f);
    u += 0x7fffu + ((u >> 16) & 1u);   // RNE
    return (u16)(u >> 16);
}
// pack two floats -> two bf16 (round-half-up) in one u32 (b in high half)
__device__ __forceinline__ u32 pk2(float a, float b) {
    u32 ua = __float_as_uint(a) + 0x8000u;
    u32 ub = __float_as_uint(b) + 0x8000u;
    return __builtin_amdgcn_perm(ub, ua, 0x07060302u);  // {ub.hi16, ua.hi16}
}

// ---------------- unified transpose + f32->bf16 convert -> packed chunks -------
// chunk(row,col): elem(rtile*16+mn, cstep*32+q*8+e) at ((rtile*16+cstep)*64+lane)*8+e
__global__ __launch_bounds__(256)
void transpA_k(const float* __restrict__ x, const float* __restrict__ wq,
               const float* __restrict__ wo, u16* __restrict__ XP,
               u16* __restrict__ WP, u16* __restrict__ WOP)
{
    const int r0 = blockIdx.x * 64;
    const int y  = blockIdx.y;
    const float* in; u16* out; int inLD, c0;
    if (y < 128) {
        const int b = y >> 5, ct = y & 31;
        in = x + (size_t)b * CDIM * LDIM; inLD = LDIM; c0 = ct * 64;
        out = XP + (size_t)b * LDIM * CDIM;
    } else if (y < 152) {
        in = wq; inLD = 1536; c0 = (y - 128) * 64; out = WP;
    } else {
        in = wo; inLD = 512;  c0 = (y - 152) * 64; out = WOP;
    }

    __shared__ __align__(16) u16 t[64][80];
    const int tt = threadIdx.x;
    const int lr = tt >> 4, lc = (tt & 15) * 4;
    #pragma unroll
    for (int i = 0; i < 4; ++i) {
        f32x4 v = *(const f32x4*)(in + (size_t)(r0 + lr + i * 16) * inLD + c0 + lc);
        #pragma unroll
        for (int j = 0; j < 4; ++j) t[lc + j][lr + i * 16] = f2b(v[j]);
    }
    __syncthreads();
    const int orow = tt >> 2, ocg = (tt & 3) * 16;
    s16x8 v0 = *(const s16x8*)&t[orow][ocg];
    s16x8 v1 = *(const s16x8*)&t[orow][ocg + 8];
    const int row   = c0 + orow;            // l (or f) index
    const int rtile = row >> 4, rr = row & 15;
    const int cstep = (r0 + ocg) >> 5;      // 32-col step within CDIM-like axis
    const int qb    = (ocg >> 3) & 3;       // 0 or 2
    u16* dst = out + ((size_t)(rtile * 16 + cstep) * 64 + qb * 16 + rr) * 8;
    *(s16x8*)dst = v0;                      // q = qb   half
    *(s16x8*)(dst + 128) = v1;              // q = qb+1 half
}

// ---------------- QKV GEMM: packed-chunk loads -> fragment-packed Q/K/V --------
__global__ __launch_bounds__(256)
void qkvgemm_bf16(const u16* __restrict__ XP, const u16* __restrict__ WP,
                  u16* __restrict__ QF, u16* __restrict__ KF, u16* __restrict__ VF)
{
    const int f0 = blockIdx.x * 64;
    const int l0 = blockIdx.y * 128;
    const int b  = blockIdx.z;
    const u16* xTb = XP + (size_t)b * LDIM * CDIM;
    const int t = threadIdx.x, w = t >> 6, lane = t & 63;
    const int mn = lane & 15, q = lane >> 4;
    const bool vpart = (f0 >= 1024);

    const u16 *Abase, *Bbase;
    int mbase, nbase;
    if (!vpart) {
        mbase = f0 + (w >> 1) * 32; nbase = l0 + (w & 1) * 64;
        Abase = WP + (size_t)mbase * CDIM; Bbase = xTb + (size_t)nbase * CDIM;
    } else {
        mbase = l0 + w * 32; nbase = f0;
        Abase = xTb + (size_t)mbase * CDIM; Bbase = WP + (size_t)nbase * CDIM;
    }

    f32x4 acc[2][4] = {};
    #pragma unroll 2
    for (int c0 = 0; c0 < CDIM; c0 += 32) {
        s16x8 a[2], bf[4];
        #pragma unroll
        for (int mi = 0; mi < 2; ++mi)
            a[mi] = *(const s16x8*)(Abase + mi * 16 * CDIM + c0 * 16 + lane * 8);
        #pragma unroll
        for (int ni = 0; ni < 4; ++ni)
            bf[ni] = *(const s16x8*)(Bbase + ni * 16 * CDIM + c0 * 16 + lane * 8);
        #pragma unroll
        for (int mi = 0; mi < 2; ++mi)
            #pragma unroll
            for (int ni = 0; ni < 4; ++ni)
                acc[mi][ni] = __builtin_amdgcn_mfma_f32_16x16x32_bf16(a[mi], bf[ni], acc[mi][ni], 0, 0, 0);
    }

    if (!vpart) {
        const int part = f0 >> 9;
        const float sc2 = (part == 0) ? 0.18033688f : 1.0f;  // 0.125*log2(e)
        u16* Tout = (part == 0) ? QF : KF;
        #pragma unroll
        for (int mi = 0; mi < 2; ++mi) {
            const int fg0 = mbase + mi * 16;
            const int h = (fg0 >> 6) & 7;
            const int d0 = (fg0 & 63) + q * 4;          // 4-aligned d base
            const int kd = d0 >> 5, qq = (d0 >> 3) & 3, e0 = d0 & 7;
            u16* T = Tout + (size_t)(b * 8 + h) * LDIM * 64;
            #pragma unroll
            for (int ni = 0; ni < 4; ++ni) {
                const int lg = nbase + ni * 16 + mn;     // L index
                size_t addr;
                if (part == 0) {                         // QF[t16][kd][lane][8]
                    const int t16 = lg >> 4, mnq = lg & 15;
                    addr = (size_t)((t16 * 2 + kd) * 512 + (qq * 16 + mnq) * 8 + e0);
                } else {                                 // KF[j64][jt][kd][lane][8], kperm absorbed
                    const int j64 = lg >> 6, r6 = lg & 63;
                    const int jt  = ((r6 >> 2) & 1) * 2 + (r6 >> 5);
                    const int mnk = ((r6 >> 3) & 3) * 4 + (r6 & 3);
                    addr = (size_t)(((j64 * 4 + jt) * 2 + kd) * 512 + (qq * 16 + mnk) * 8 + e0);
                }
                u16x4 pk;
                #pragma unroll
                for (int r = 0; r < 4; ++r) pk[r] = f2b(acc[mi][ni][r] * sc2);
                *(u16x4*)(T + addr) = pk;
            }
        }
    } else {
        #pragma unroll
        for (int ni = 0; ni < 4; ++ni) {
            const int fg = nbase + ni * 16 + mn;
            const int h = (fg >> 6) & 7;
            const int d = fg & 63;
            const int dt = d >> 4, mnv = d & 15;
            u16* Vb = VF + (size_t)(b * 8 + h) * LDIM * 64;
            #pragma unroll
            for (int mi = 0; mi < 2; ++mi) {
                const int lg0 = mbase + mi * 16 + q * 4;    // 4-aligned j base
                const int j64 = lg0 >> 6, j6 = lg0 & 63;
                const int kj = j6 >> 5, qq = (j6 >> 3) & 3, e0 = j6 & 7;
                const size_t addr = (size_t)(((j64 * 2 + kj) * 4 + dt) * 512 + (qq * 16 + mnv) * 8 + e0);
                u16x4 pk;
                #pragma unroll
                for (int r = 0; r < 4; ++r) pk[r] = f2b(acc[mi][ni][r]);
                *(u16x4*)(Vb + addr) = pk;
            }
        }
    }
}

// ---------------- Flash attention: 64 i-rows/block, LDS-free P, 2-wave j-split --
// grid (x=bh 32, y=32), 128 threads (2 waves). All loads lane-contiguous 1KB.
// Each wave: 4 ibt sub-tiles (64 i) x 16 j-tiles (its j-half). K/V traffic halved
// vs r4; per-iter independent work doubled (latency cover). V prefetch staggered.
__global__ __launch_bounds__(128)
void attn_k(const u16* __restrict__ QF, const u16* __restrict__ KF,
            const u16* __restrict__ VF, u16* __restrict__ aoP)
{
    const int bh = blockIdx.x;
    const int b = bh >> 3, h = bh & 7;
    const u16* Qh = QF + (size_t)bh * LDIM * 64;
    const u16* Kh = KF + (size_t)bh * LDIM * 64;
    const u16* Vh = VF + (size_t)bh * LDIM * 64;

    __shared__ __align__(16) float o_sh[64][68];   // +4 pad (2-way = free)
    __shared__ float lp_sh[64];

    const int tid = threadIdx.x;
    const int wv = tid >> 6;
    const int lane = tid & 63;
    const int mn = lane & 15, q = lane >> 4;
    const int ib64 = blockIdx.y;         // 64-row i-block
    const int TH = 16;                   // j-tiles per wave (of 32 total)
    const int tbase = wv * TH;

    s16x8 aq[4][2];
    #pragma unroll
    for (int ibt = 0; ibt < 4; ++ibt) {
        const int t16 = ib64 * 4 + ibt;
        #pragma unroll
        for (int kd = 0; kd < 2; ++kd)
            aq[ibt][kd] = *(const s16x8*)(Qh + (size_t)((t16 * 2 + kd) * 512) + lane * 8);
    }

    f32x4 o_acc[4][4] = {};
    float lp[4] = {0.f, 0.f, 0.f, 0.f};

    // preload this wave's tile-0 K/V fragments (fully coalesced)
    s16x8 kc[2][4], vc[2][4];
    {
        const u16* Kt = Kh + (size_t)tbase * 4096;
        const u16* Vt = Vh + (size_t)tbase * 4096;
        #pragma unroll
        for (int kd = 0; kd < 2; ++kd)
            #pragma unroll
            for (int jt = 0; jt < 4; ++jt)
                kc[kd][jt] = *(const s16x8*)(Kt + ((jt * 2 + kd) << 9) + (lane << 3));
        #pragma unroll
        for (int kj = 0; kj < 2; ++kj)
            #pragma unroll
            for (int dt = 0; dt < 4; ++dt)
                vc[kj][dt] = *(const s16x8*)(Vt + ((kj * 4 + dt) << 9) + (lane << 3));
    }

    #pragma unroll 2
    for (int jj = 0; jj < TH; ++jj) {
        const int tn = tbase + ((jj + 1) & (TH - 1));   // last iter wraps (L2-hot)
        const u16* Kt = Kh + (size_t)tn * 4096;
        const u16* Vt = Vh + (size_t)tn * 4096;

        // issue next tile's K loads FIRST
        s16x8 kn[2][4];
        #pragma unroll
        for (int kd = 0; kd < 2; ++kd)
            #pragma unroll
            for (int jt = 0; jt < 4; ++jt)
                kn[kd][jt] = *(const s16x8*)(Kt + ((jt * 2 + kd) << 9) + (lane << 3));

        // S^T = K.Q^T on current K: 32 MFMA (4 ibt)
        f32x4 s[4][4] = {};
        #pragma unroll
        for (int kd = 0; kd < 2; ++kd)
            #pragma unroll
            for (int jt = 0; jt < 4; ++jt)
                #pragma unroll
                for (int ibt = 0; ibt < 4; ++ibt)
                    s[ibt][jt] = __builtin_amdgcn_mfma_f32_16x16x32_bf16(kc[kd][jt], aq[ibt][kd], s[ibt][jt], 0, 0, 0);

        // issue next tile's V loads AFTER QK (staggered: caps VGPR peak, still ~1 iter cover)
        s16x8 vn[2][4];
        #pragma unroll
        for (int kj = 0; kj < 2; ++kj)
            #pragma unroll
            for (int dt = 0; dt < 4; ++dt)
                vn[kj][dt] = *(const s16x8*)(Vt + ((kj * 4 + dt) << 9) + (lane << 3));

        // p = 2^s; build PV B-fragments fully in-register (lane-local j-slots).
        #pragma unroll
        for (int kj = 0; kj < 2; ++kj) {
            s16x8 ap[4];
            #pragma unroll
            for (int ibt = 0; ibt < 4; ++ibt) {
                float pa0 = __builtin_amdgcn_exp2f(s[ibt][kj][0]);
                float pa1 = __builtin_amdgcn_exp2f(s[ibt][kj][1]);
                float pa2 = __builtin_amdgcn_exp2f(s[ibt][kj][2]);
                float pa3 = __builtin_amdgcn_exp2f(s[ibt][kj][3]);
                float pb0 = __builtin_amdgcn_exp2f(s[ibt][kj + 2][0]);
                float pb1 = __builtin_amdgcn_exp2f(s[ibt][kj + 2][1]);
                float pb2 = __builtin_amdgcn_exp2f(s[ibt][kj + 2][2]);
                float pb3 = __builtin_amdgcn_exp2f(s[ibt][kj + 2][3]);
                lp[ibt] += ((pa0 + pa1) + (pa2 + pa3)) + ((pb0 + pb1) + (pb2 + pb3));
                union { s16x8 v; u32 w[4]; } u;
                u.w[0] = pk2(pa0, pa1);
                u.w[1] = pk2(pa2, pa3);
                u.w[2] = pk2(pb0, pb1);
                u.w[3] = pk2(pb2, pb3);
                ap[ibt] = u.v;
            }
            #pragma unroll
            for (int dt = 0; dt < 4; ++dt)
                #pragma unroll
                for (int ibt = 0; ibt < 4; ++ibt)
                    o_acc[ibt][dt] = __builtin_amdgcn_mfma_f32_16x16x32_bf16(vc[kj][dt], ap[ibt], o_acc[ibt][dt], 0, 0, 0);
        }

        // rotate prefetched registers
        #pragma unroll
        for (int kd = 0; kd < 2; ++kd)
            #pragma unroll
            for (int jt = 0; jt < 4; ++jt)
                kc[kd][jt] = kn[kd][jt];
        #pragma unroll
        for (int kj = 0; kj < 2; ++kj)
            #pragma unroll
            for (int dt = 0; dt < 4; ++dt)
                vc[kj][dt] = vn[kj][dt];
    }

    #pragma unroll
    for (int ibt = 0; ibt < 4; ++ibt) {
        lp[ibt] += __shfl_xor(lp[ibt], 16);
        lp[ibt] += __shfl_xor(lp[ibt], 32);
    }

    // combine the two waves' j-partials: plain addition (sum-normalized softmax)
    if (wv == 1) {
        #pragma unroll
        for (int ibt = 0; ibt < 4; ++ibt) {
            #pragma unroll
            for (int dt = 0; dt < 4; ++dt)
                *(f32x4*)&o_sh[ibt * 16 + mn][dt * 16 + q * 4] = o_acc[ibt][dt];
            if (q == 0) lp_sh[ibt * 16 + mn] = lp[ibt];
        }
    }
    __syncthreads();
    if (wv == 0) {
        u16* Ab = aoP + (size_t)b * LDIM * 512;
        #pragma unroll
        for (int ibt = 0; ibt < 4; ++ibt) {
            const float rinv = 1.0f / (lp[ibt] + lp_sh[ibt * 16 + mn]);
            const int ltile = ib64 * 4 + ibt;
            #pragma unroll
            for (int dt = 0; dt < 4; ++dt) {
                f32x4 os = *(const f32x4*)&o_sh[ibt * 16 + mn][dt * 16 + q * 4];
                u16x4 pk;
                #pragma unroll
                for (int r = 0; r < 4; ++r)
                    pk[r] = f2b((o_acc[ibt][dt][r] + os[r]) * rinv);
                // packed-chunk store: col = h*64 + dt*16 + q*4 + r
                const int cstep = h * 2 + (dt >> 1);
                const int lanep = ((dt & 1) * 2 + (q >> 1)) * 16 + mn;
                u16* dst = Ab + ((size_t)(ltile * 16 + cstep) * 64 + lanep) * 8 + (q & 1) * 4;
                *(u16x4*)dst = pk;
            }
        }
    }
}

// ---------------- Output GEMM: packed-chunk loads ----------------
__global__ __launch_bounds__(256)
void outgemm_d(const u16* __restrict__ aoP, const u16* __restrict__ WOP,
               const float* __restrict__ bias, float* __restrict__ Y)
{
    const int f0 = blockIdx.x * 64;
    const int l0 = blockIdx.y * 128;
    const int b  = blockIdx.z;
    const int t = threadIdx.x, w = t >> 6, lane = t & 63;
    const int mn = lane & 15, q = lane >> 4;
    const int mbase = f0 + (w >> 1) * 32;
    const int nbase = l0 + (w & 1) * 64;
    const u16* Abase = WOP + (size_t)mbase * CDIM;
    const u16* Bbase = aoP + ((size_t)b * LDIM + nbase) * CDIM;
    float* Yb = Y + (size_t)b * CDIM * LDIM;

    f32x4 acc[2][4] = {};
    #pragma unroll 2
    for (int c0 = 0; c0 < CDIM; c0 += 32) {
        s16x8 a[2], bf[4];
        #pragma unroll
        for (int mi = 0; mi < 2; ++mi)
            a[mi] = *(const s16x8*)(Abase + mi * 16 * CDIM + c0 * 16 + lane * 8);
        #pragma unroll
        for (int ni = 0; ni < 4; ++ni)
            bf[ni] = *(const s16x8*)(Bbase + ni * 16 * CDIM + c0 * 16 + lane * 8);
        #pragma unroll
        for (int mi = 0; mi < 2; ++mi)
            #pragma unroll
            for (int ni = 0; ni < 4; ++ni)
                acc[mi][ni] = __builtin_amdgcn_mfma_f32_16x16x32_bf16(a[mi], bf[ni], acc[mi][ni], 0, 0, 0);
    }
    #pragma unroll
    for (int mi = 0; mi < 2; ++mi)
        #pragma unroll
        for (int r = 0; r < 4; ++r) {
            const int f = mbase + mi * 16 + q * 4 + r;
            const float bs = bias[f];
            #pragma unroll
            for (int ni = 0; ni < 4; ++ni)
                Yb[(size_t)f * LDIM + nbase + ni * 16 + mn] = acc[mi][ni][r] + bs;
        }
}

extern "C" void kernel_launch(void* const* d_in, const int* in_sizes, int n_in,
                              void* d_out, int out_size, void* d_ws, size_t ws_size,
                              hipStream_t stream) {
    const float *x = nullptr, *w_qkv = nullptr, *w_out = nullptr, *b_out = nullptr;
    for (int i = 0; i < n_in; ++i) {
        switch (in_sizes[i]) {
            case 4 * 512 * 2048: x     = (const float*)d_in[i]; break;
            case 512 * 1536:     w_qkv = (const float*)d_in[i]; break;
            case 512 * 512:      w_out = (const float*)d_in[i]; break;
            case 512:            b_out = (const float*)d_in[i]; break;
        }
    }
    float* out = (float*)d_out;                 // [4][512][2048] f32

    const size_t SLAB = (size_t)BATCH * LDIM * 512;      // 4194304 elems
    u16* WOP = (u16*)d_ws;                               // [512 rows][512] packed
    u16* XP  = WOP + (size_t)512 * 512;                  // [4][2048 rows][512] packed
    u16* WP  = XP + SLAB;                                // [1536 rows][512] packed
    u16* QF  = WP + (size_t)1536 * 512;                  // [32][2048*64] attn-packed
    u16* KF  = QF + SLAB;                                // [32][2048*64] attn-packed
    u16* VF  = KF + SLAB;                                // [32][2048*64] attn-packed
    u16* aoP = VF + SLAB;                                // [4][2048 rows][512] packed

    transpA_k<<<dim3(8, 160), 256, 0, stream>>>(x, w_qkv, w_out, XP, WP, WOP);
    qkvgemm_bf16<<<dim3(24, 16, BATCH), 256, 0, stream>>>(XP, WP, QF, KF, VF);
    attn_k<<<dim3(32, 32), 128, 0, stream>>>(QF, KF, VF, aoP);
    outgemm_d<<<dim3(8, 16, BATCH), 256, 0, stream>>>(aoP, WOP, b_out, out);
}